// Round 13
// baseline (349.028 us; speedup 1.0000x reference)
//
#include <hip/hip_runtime.h>
#include <hip/hip_bf16.h>
#include <stdint.h>

#define NTOK 2048
#define NB 4
#define DM 256
#define HD 64
#define NE 65536
#define SCAP 128
#define NKSL 4            // K-slices for attention partials
#define LIVE_ROWS 6272    // mask4 rows [0, LIVE_ROWS) hold live scratch until gemm; written last

typedef __bf16 bf16x8 __attribute__((ext_vector_type(8)));
typedef float f32x4 __attribute__((ext_vector_type(4)));

#define MFMA16 __builtin_amdgcn_mfma_f32_16x16x32_bf16

__device__ __forceinline__ unsigned short f2bf(float f) {
    union { float f; uint32_t u; } v; v.f = f;
    return (unsigned short)((v.u + 0x7fffu + ((v.u >> 16) & 1u)) >> 16);
}

// ---------------- F0: ws-zero + W^T + fused {x cast + y = x@Wg1} ----------------
__global__ __launch_bounds__(256) void k_prep(const float* __restrict__ x,
                       unsigned short* __restrict__ xb,
                       const float* __restrict__ W0, const float* __restrict__ W1,
                       const float* __restrict__ W2, const float* __restrict__ W3,
                       unsigned short* __restrict__ WT, float4* __restrict__ wsz,
                       const float* __restrict__ Wg1, float* __restrict__ y) {
    __shared__ float xs[16][256];
    int bid = blockIdx.x, t = threadIdx.x;
    if (bid < 132) {
        wsz[bid * 256 + t] = float4{0.f, 0.f, 0.f, 0.f};
    } else if (bid < 1156) {
        int b2 = bid - 132;                        // [0,1024)
        int sel = b2 >> 8;
        const float* W = sel == 0 ? W0 : sel == 1 ? W1 : sel == 2 ? W2 : W3;
        int e = (b2 & 255) * 256 + t;              // e = n*256 + k
        int n = e >> 8, k = e & 255;
        WT[sel * 65536 + e] = f2bf(W[k * 256 + n]);
    } else {
        // 16 tokens per block: load x tile, emit bf16 cast, compute y = x@Wg1
        int m0 = (bid - 1156) * 16;
        #pragma unroll
        for (int j = 0; j < 16; ++j) {
            float v = x[(size_t)(m0 + j) * DM + t];
            xs[j][t] = v;
            xb[(size_t)(m0 + j) * DM + t] = f2bf(v);
        }
        __syncthreads();
        int c = t & 127, g = t >> 7;               // g: token half (8 tokens)
        float acc[8] = {0.f, 0.f, 0.f, 0.f, 0.f, 0.f, 0.f, 0.f};
        const float* xr = &xs[g * 8][0];
        #pragma unroll 4
        for (int r = 0; r < DM; ++r) {
            float w = Wg1[r * 128 + c];
            #pragma unroll
            for (int j = 0; j < 8; ++j) acc[j] += xr[j * 256 + r] * w;
        }
        #pragma unroll
        for (int j = 0; j < 8; ++j) y[(size_t)(m0 + g * 8 + j) * 128 + c] = acc[j];
    }
}

// ---------------- edges: fused count + bucket-scatter + bitmap ----------------
__global__ void k_edges(const int* __restrict__ ei, uint32_t* __restrict__ cursor,
                        uint32_t* __restrict__ scol, uint32_t* __restrict__ ebits) {
    int e = blockIdx.x * 256 + threadIdx.x;
    int r = ei[e];
    int c = ei[NE + e];
    uint32_t slot = atomicAdd(&cursor[r], 1u);
    if (slot < SCAP) scol[r * SCAP + slot] = (uint32_t)c;
    atomicOr(&ebits[r * 64 + (c >> 5)], 1u << (c & 31));
}

// ---------------- fused: GNN-on-y (blocks [0,2048)) + QKV GEMM ([2048,3584)) ----------------
// K out: KT[bh][nb=tok>>4][nw=tok&15][d]   V out: VT3[bh][nb=tok>>5][d][nw=tok&31]
__global__ __launch_bounds__(256) void k_gnn_qkv(
    const float* __restrict__ y, const uint32_t* __restrict__ cursor,
    const uint32_t* __restrict__ scol,
    const float* __restrict__ bg1, const float* __restrict__ Wg2,
    const float* __restrict__ bg2, float* __restrict__ topo,
    const unsigned short* __restrict__ xbf, const unsigned short* __restrict__ WT,
    const float* __restrict__ bq, const float* __restrict__ bk, const float* __restrict__ bv,
    unsigned short* __restrict__ qo, unsigned short* __restrict__ kt,
    unsigned short* __restrict__ vt3) {
    int bid = blockIdx.x, t = threadIdx.x;
    if (bid < 2048) {
        // gather y[col] (128 f32 per batch), f64 accumulate; batches (bp, bp+2)
        int i = bid;
        int d = t & 127, bp = t >> 7;
        uint32_t cnt = cursor[i]; if (cnt > SCAP) cnt = SCAP;
        const uint32_t* sc = scol + i * SCAP;
        const float* yA = y + (size_t)(bp * NTOK) * 128 + d;        // batch bp
        const float* yB = y + (size_t)((bp + 2) * NTOK) * 128 + d;  // batch bp+2
        double A0 = 0, A1 = 0, A2 = 0, A3 = 0;
        double B0 = 0, B1 = 0, B2 = 0, B3 = 0;
        uint32_t e = 0;
        for (; e + 3 < cnt; e += 4) {
            int c0 = sc[e] << 7, c1 = sc[e + 1] << 7;
            int c2 = sc[e + 2] << 7, c3 = sc[e + 3] << 7;
            A0 += (double)yA[c0]; A1 += (double)yA[c1];
            A2 += (double)yA[c2]; A3 += (double)yA[c3];
            B0 += (double)yB[c0]; B1 += (double)yB[c1];
            B2 += (double)yB[c2]; B3 += (double)yB[c3];
        }
        for (; e < cnt; ++e) {
            int c0 = sc[e] << 7;
            A0 += (double)yA[c0];
            B0 += (double)yB[c0];
        }
        double hA = (A0 + A1) + (A2 + A3) + (double)bg1[d];
        double hB = (B0 + B1) + (B2 + B3) + (double)bg1[d];
        double w2 = (double)Wg2[d];
        double vA = (hA > 0 ? hA : 0.0) * w2;   // batch bp
        double vB = (hB > 0 ? hB : 0.0) * w2;   // batch bp+2
        #pragma unroll
        for (int s = 32; s >= 1; s >>= 1) {
            vA += __shfl_xor(vA, s);
            vB += __shfl_xor(vB, s);
        }
        __shared__ double red[4][2];
        int wid = t >> 6;
        if ((t & 63) == 0) { red[wid][0] = vA; red[wid][1] = vB; }
        __syncthreads();
        if (t == 0) {
            double bb = (double)bg2[0];
            topo[0 * NTOK + i] = (float)(red[0][0] + red[1][0] + bb);
            topo[2 * NTOK + i] = (float)(red[0][1] + red[1][1] + bb);
            topo[1 * NTOK + i] = (float)(red[2][0] + red[3][0] + bb);
            topo[3 * NTOK + i] = (float)(red[2][1] + red[3][1] + bb);
        }
    } else {
        int b2 = bid - 2048;
        int z = b2 >> 9, r2 = b2 & 511;
        const unsigned short* W = WT + z * 65536;
        const float* bias = z == 0 ? bq : z == 1 ? bk : bv;

        int lane = t & 63, w = t >> 6;
        int l15 = lane & 15, grp = lane >> 4;
        int mbase = (r2 & 127) * 64 + w * 16;
        int nbase = (r2 >> 7) * 64;
        f32x4 acc0 = {0,0,0,0}, acc1 = {0,0,0,0}, acc2 = {0,0,0,0}, acc3 = {0,0,0,0};
        const unsigned short* ap = xbf + (size_t)(mbase + l15) * DM + grp * 8;
        const unsigned short* bp2 = W + (size_t)(nbase + l15) * DM + grp * 8;
        #pragma unroll
        for (int k0 = 0; k0 < DM; k0 += 32) {
            bf16x8 af = *(const bf16x8*)(ap + k0);
            acc0 = MFMA16(af, *(const bf16x8*)(bp2 + k0), acc0, 0, 0, 0);
            acc1 = MFMA16(af, *(const bf16x8*)(bp2 + 16 * DM + k0), acc1, 0, 0, 0);
            acc2 = MFMA16(af, *(const bf16x8*)(bp2 + 32 * DM + k0), acc2, 0, 0, 0);
            acc3 = MFMA16(af, *(const bf16x8*)(bp2 + 48 * DM + k0), acc3, 0, 0, 0);
        }
        f32x4 accs[4] = {acc0, acc1, acc2, acc3};
        #pragma unroll
        for (int ct = 0; ct < 4; ++ct) {
            #pragma unroll
            for (int r = 0; r < 4; ++r) {
                int m = mbase + grp * 4 + r;            // token (w/in 8192)
                int n = nbase + ct * 16 + l15;          // feature (h*64+d)
                float v = accs[ct][r] + bias[n];
                if (z == 0) {
                    qo[(size_t)m * DM + n] = f2bf(v);
                } else {
                    int b = m >> 11, tok = m & 2047, h = n >> 6, d = n & 63;
                    int bh = (b << 2) + h;
                    if (z == 1) {
                        kt[(size_t)bh * 131072 + (tok >> 4) * 1024 + (tok & 15) * 64 + d] = f2bf(v);
                    } else {
                        vt3[(size_t)bh * 131072 + (tok >> 5) * 2048 + d * 32 + (tok & 31)] = f2bf(v);
                    }
                }
            }
        }
    }
}

// ---------------- top-k column mask (stable tie-break = lax.top_k), float4 scan ----------------
__global__ __launch_bounds__(256) void k_topk(const float* __restrict__ topo,
                                              uint32_t* __restrict__ colbits) {
    int b = blockIdx.y, t = threadIdx.x;
    int i = blockIdx.x * 256 + t;
    __shared__ float4 sc4[NTOK / 4];
    const float4* tp = (const float4*)(topo + b * NTOK);
    for (int j = t; j < NTOK / 4; j += 256) sc4[j] = tp[j];
    __syncthreads();
    float si = ((const float*)sc4)[i];
    int rank = 0;
    #pragma unroll 2
    for (int jj = 0; jj < NTOK / 4; ++jj) {
        float4 v = sc4[jj];
        int j0 = jj * 4;
        rank += (v.x > si) || (v.x == si && (j0    ) < i);
        rank += (v.y > si) || (v.y == si && (j0 + 1) < i);
        rank += (v.z > si) || (v.z == si && (j0 + 2) < i);
        rank += (v.w > si) || (v.w == si && (j0 + 3) < i);
    }
    unsigned long long m = __ballot(rank < 1024);
    int lane = t & 63;
    if (lane == 0)       colbits[b * 64 + (i >> 5)] = (uint32_t)m;
    else if (lane == 32) colbits[b * 64 + (i >> 5)] = (uint32_t)(m >> 32);
}

// ---------------- mask4 row writer (non-temporal stores: keep L2 for K/V) ----------------
__device__ __forceinline__ void mask_row(int rowidx, const uint32_t* __restrict__ eb,
                                         const uint32_t* __restrict__ cb,
                                         float* __restrict__ mout) {
    int t = threadIdx.x;
    int b = rowidx >> 13;
    int i = rowidx & 2047;
    int j0 = t << 3;
    uint32_t mw = eb[i * 64 + (j0 >> 5)] | cb[b * 64 + (j0 >> 5)];
    int sh = j0 & 31;
    f32x4 v0, v1;
    v0[0] = ((mw >> sh) & 1u) ? 1.f : 0.f;
    v0[1] = ((mw >> (sh + 1)) & 1u) ? 1.f : 0.f;
    v0[2] = ((mw >> (sh + 2)) & 1u) ? 1.f : 0.f;
    v0[3] = ((mw >> (sh + 3)) & 1u) ? 1.f : 0.f;
    v1[0] = ((mw >> (sh + 4)) & 1u) ? 1.f : 0.f;
    v1[1] = ((mw >> (sh + 5)) & 1u) ? 1.f : 0.f;
    v1[2] = ((mw >> (sh + 6)) & 1u) ? 1.f : 0.f;
    v1[3] = ((mw >> (sh + 7)) & 1u) ? 1.f : 0.f;
    float* p = mout + (size_t)rowidx * NTOK + j0;
    __builtin_nontemporal_store(v0, (f32x4*)p);
    __builtin_nontemporal_store(v1, (f32x4*)(p + 4));
}

// ---------------- fused: attention partials (blocks [0,2048)) + mask rows >= LIVE_ROWS ----------------
// Fixed-shift softmax: p = exp(s - 8); slices combine additively.
__global__ __launch_bounds__(256) void k_attn_mask(const unsigned short* __restrict__ Q,
                                                   const unsigned short* __restrict__ KT,
                                                   const unsigned short* __restrict__ VT3,
                                                   const uint32_t* __restrict__ ebits,
                                                   const uint32_t* __restrict__ colbits,
                                                   float* __restrict__ po,
                                                   float* __restrict__ pl,
                                                   float* __restrict__ mout) {
    int bid = blockIdx.x;
    if (bid >= 2048) {
        mask_row(bid - 2048 + LIVE_ROWS, ebits, colbits, mout);
        return;
    }
    int lane = threadIdx.x & 63, w = threadIdx.x >> 6;
    int l15 = lane & 15, grp = lane >> 4;
    int ks = bid >> 9;                  // K-slice 0..NKSL-1
    int bh = (bid >> 5) & 15, b = bh >> 2, h = bh & 3;
    int q = (bid & 31) * 64 + w * 16 + l15;

    const unsigned short* qp = Q + (size_t)(b * NTOK + q) * DM + h * HD + grp * 8;
    bf16x8 qf0 = *(const bf16x8*)(qp);
    bf16x8 qf1 = *(const bf16x8*)(qp + 32);
    const unsigned short* kbase = KT + (size_t)bh * 131072 + l15 * 64 + grp * 8;
    const unsigned short* vbase = VT3 + (size_t)bh * 131072 + l15 * 32 + grp * 8;
    const uint32_t* eb = ebits + q * 64;
    const uint32_t* cbp = colbits + b * 64;

    f32x4 o0 = {0,0,0,0}, o1 = {0,0,0,0}, o2 = {0,0,0,0}, o3 = {0,0,0,0};
    float psum = 0.f;

    int kb0 = ks * (NTOK / NKSL);
    for (int kb = kb0; kb < kb0 + NTOK / NKSL; kb += 32) {
        const unsigned short* kp0 = kbase + (kb >> 4) * 1024;
        f32x4 st0 = {0,0,0,0}, st1 = {0,0,0,0};
        st0 = MFMA16(*(const bf16x8*)(kp0), qf0, st0, 0, 0, 0);
        st0 = MFMA16(*(const bf16x8*)(kp0 + 32), qf1, st0, 0, 0, 0);
        st1 = MFMA16(*(const bf16x8*)(kp0 + 1024), qf0, st1, 0, 0, 0);
        st1 = MFMA16(*(const bf16x8*)(kp0 + 1024 + 32), qf1, st1, 0, 0, 0);

        uint32_t mw = eb[kb >> 5] | cbp[kb >> 5];
        float p[8];
        #pragma unroll
        for (int r = 0; r < 4; ++r) {
            int p0 = grp * 4 + r;
            p[r]     = ((mw >> p0) & 1u)        ? __expf(st0[r] * 0.125f - 8.0f) : 0.f;
            p[4 + r] = ((mw >> (16 + p0)) & 1u) ? __expf(st1[r] * 0.125f - 8.0f) : 0.f;
        }
        #pragma unroll
        for (int j = 0; j < 8; ++j) psum += p[j];

        uint32_t pk00, pk01, pk10, pk11;
        asm("v_cvt_pk_bf16_f32 %0, %1, %2" : "=v"(pk00) : "v"(p[0]), "v"(p[1]));
        asm("v_cvt_pk_bf16_f32 %0, %1, %2" : "=v"(pk01) : "v"(p[2]), "v"(p[3]));
        asm("v_cvt_pk_bf16_f32 %0, %1, %2" : "=v"(pk10) : "v"(p[4]), "v"(p[5]));
        asm("v_cvt_pk_bf16_f32 %0, %1, %2" : "=v"(pk11) : "v"(p[6]), "v"(p[7]));
        union { uint32_t u[4]; bf16x8 v; } pf;
        #pragma unroll
        for (int wi = 0; wi < 4; ++wi) {
            int src = (((grp * 2 + (wi >> 1)) & 3) << 4) | l15;
            uint32_t lo = (uint32_t)__shfl((int)((wi & 1) ? pk01 : pk00), src);
            uint32_t hi = (uint32_t)__shfl((int)((wi & 1) ? pk11 : pk10), src);
            pf.u[wi] = (lane >= 32) ? hi : lo;
        }

        const unsigned short* vk = vbase + (kb >> 5) * 2048;
        o0 = MFMA16(*(const bf16x8*)(vk),            pf.v, o0, 0, 0, 0);
        o1 = MFMA16(*(const bf16x8*)(vk + 16 * 32),  pf.v, o1, 0, 0, 0);
        o2 = MFMA16(*(const bf16x8*)(vk + 32 * 32),  pf.v, o2, 0, 0, 0);
        o3 = MFMA16(*(const bf16x8*)(vk + 48 * 32),  pf.v, o3, 0, 0, 0);
    }
    psum += __shfl_xor(psum, 16);
    psum += __shfl_xor(psum, 32);

    float* pb = po + (((size_t)(ks * 16 + bh) * NTOK + q) * HD);
    __builtin_nontemporal_store(o0, (f32x4*)(pb + 0 * 16 + grp * 4));
    __builtin_nontemporal_store(o1, (f32x4*)(pb + 1 * 16 + grp * 4));
    __builtin_nontemporal_store(o2, (f32x4*)(pb + 2 * 16 + grp * 4));
    __builtin_nontemporal_store(o3, (f32x4*)(pb + 3 * 16 + grp * 4));
    if (grp == 0) pl[(size_t)(ks * 16 + bh) * NTOK + q] = psum;
}

// ---------------- combine K-slice partials -> normalized bf16 attention out ----------------
__global__ __launch_bounds__(256) void k_fin(const float* __restrict__ po,
                                             const float* __restrict__ pl,
                                             unsigned short* __restrict__ aoutb) {
    const size_t SL = (size_t)16 * NTOK * HD;   // po slice stride
    const size_t SLP = (size_t)16 * NTOK;       // pl slice stride
    int tid = blockIdx.x * 256 + threadIdx.x;   // 262144 total
    int dc = tid & 7;
    int q = (tid >> 3) & 2047;
    int bh = tid >> 14;
    size_t rb = ((size_t)bh * NTOK + q) * HD + dc * 8;
    f32x4 s0 = __builtin_nontemporal_load((const f32x4*)(po + rb));
    f32x4 s1 = __builtin_nontemporal_load((const f32x4*)(po + rb + 4));
    #pragma unroll
    for (int ks = 1; ks < NKSL; ++ks) {
        f32x4 a = __builtin_nontemporal_load((const f32x4*)(po + ks * SL + rb));
        f32x4 c = __builtin_nontemporal_load((const f32x4*)(po + ks * SL + rb + 4));
        s0 += a;
        s1 += c;
    }
    float l = 0.f;
    #pragma unroll
    for (int ks = 0; ks < NKSL; ++ks) l += pl[ks * SLP + (size_t)bh * NTOK + q];
    float inv = 1.f / l;
    int b = bh >> 2, h = bh & 3;
    union { ushort4 u4[2]; uint4 v; } out;
    out.u4[0].x = f2bf(s0[0] * inv); out.u4[0].y = f2bf(s0[1] * inv);
    out.u4[0].z = f2bf(s0[2] * inv); out.u4[0].w = f2bf(s0[3] * inv);
    out.u4[1].x = f2bf(s1[0] * inv); out.u4[1].y = f2bf(s1[1] * inv);
    out.u4[1].z = f2bf(s1[2] * inv); out.u4[1].w = f2bf(s1[3] * inv);
    *(uint4*)(aoutb + ((size_t)(b * NTOK + q) * DM) + h * HD + dc * 8) = out.v;
}

// ---------------- output projection GEMM (f32 out) ----------------
__global__ __launch_bounds__(256) void k_gemm_o(const unsigned short* __restrict__ A,
                                                const unsigned short* __restrict__ WT,
                                                const float* __restrict__ bias,
                                                float* __restrict__ out) {
    int bid = blockIdx.x;
    int lane = threadIdx.x & 63, w = threadIdx.x >> 6;
    int l15 = lane & 15, grp = lane >> 4;
    int mbase = (bid & 127) * 64 + w * 16;
    int nbase = (bid >> 7) * 64;
    f32x4 acc0 = {0,0,0,0}, acc1 = {0,0,0,0}, acc2 = {0,0,0,0}, acc3 = {0,0,0,0};
    const unsigned short* ap = A + (size_t)(mbase + l15) * DM + grp * 8;
    const unsigned short* bp = WT + (size_t)(nbase + l15) * DM + grp * 8;
    #pragma unroll
    for (int k0 = 0; k0 < DM; k0 += 32) {
        bf16x8 af = *(const bf16x8*)(ap + k0);
        acc0 = MFMA16(af, *(const bf16x8*)(bp + k0), acc0, 0, 0, 0);
        acc1 = MFMA16(af, *(const bf16x8*)(bp + 16 * DM + k0), acc1, 0, 0, 0);
        acc2 = MFMA16(af, *(const bf16x8*)(bp + 32 * DM + k0), acc2, 0, 0, 0);
        acc3 = MFMA16(af, *(const bf16x8*)(bp + 48 * DM + k0), acc3, 0, 0, 0);
    }
    f32x4 accs[4] = {acc0, acc1, acc2, acc3};
    #pragma unroll
    for (int ct = 0; ct < 4; ++ct) {
        #pragma unroll
        for (int r = 0; r < 4; ++r) {
            int m = mbase + grp * 4 + r;
            int n = nbase + ct * 16 + l15;
            out[(size_t)m * DM + n] = accs[ct][r] + bias[n];
        }
    }
}

// ---------------- deferred mask4 rows [0, LIVE_ROWS): overwrite scratch last ----------------
__global__ void k_mask4b(const uint32_t* __restrict__ ebits, const uint32_t* __restrict__ colbits,
                         float* __restrict__ mout) {
    mask_row(blockIdx.x, ebits, colbits, mout);
}

extern "C" void kernel_launch(void* const* d_in, const int* in_sizes, int n_in,
                              void* d_out, int out_size, void* d_ws, size_t ws_size,
                              hipStream_t stream) {
    const float* x   = (const float*)d_in[0];
    const int*   ei  = (const int*)d_in[1];          // int64 in reference -> int32 here
    const float* Wq  = (const float*)d_in[2];
    const float* bq  = (const float*)d_in[3];
    const float* Wk  = (const float*)d_in[4];
    const float* bk  = (const float*)d_in[5];
    const float* Wv  = (const float*)d_in[6];
    const float* bv  = (const float*)d_in[7];
    const float* Wo  = (const float*)d_in[8];
    const float* bo  = (const float*)d_in[9];
    const float* Wg1 = (const float*)d_in[10];
    const float* bg1 = (const float*)d_in[11];
    const float* Wg2 = (const float*)d_in[12];
    const float* bg2 = (const float*)d_in[13];

    float* out0  = (float*)d_out;
    float* mask4 = out0 + (size_t)NB * NTOK * DM;

    // Scratch layout: everything live during/after attention sits in the first
    // 49 MB (= LIVE_ROWS mask rows): [qbf|kt|vt3|wt|aoutb|po|pl]; dead-by-attn
    // [xbf|scol|y] at 49..58 MB. k_attn_mask writes rows >= LIVE_ROWS overlapped
    // with attention; k_mask4b rewrites rows [0, LIVE_ROWS) last.
    uint8_t* big = (uint8_t*)mask4;
    unsigned short* qbf   = (unsigned short*)(big);                          // 0..4 MB
    unsigned short* kt    = (unsigned short*)(big + (4u  << 20));            // 4..8 MB
    unsigned short* vt3   = (unsigned short*)(big + (8u  << 20));            // 8..12 MB
    unsigned short* wt    = (unsigned short*)(big + (12u << 20));            // 12..12.5 MB
    unsigned short* aoutb = (unsigned short*)(big + (12u << 20) + (512u << 10)); // 12.5..16.5 MB
    float*          po    = (float*)(big + (16u << 20) + (512u << 10));      // 16.5..48.5 MB
    float*          pl    = (float*)(big + (48u << 20) + (512u << 10));      // 48.5..49 MB
    unsigned short* xbf   = (unsigned short*)(big + (49u << 20));            // 49..53 MB
    uint32_t*       scol  = (uint32_t*)(big + (53u << 20));                  // 53..54 MB
    float*          y     = (float*)(big + (54u << 20));                     // 54..58 MB

    // Small scratch in d_ws
    uint8_t* ws = (uint8_t*)d_ws;
    uint32_t* cursor  = (uint32_t*)(ws);               // 8 KB  (atomic; zeroed by k_prep)
    uint32_t* ebits   = (uint32_t*)(ws + (16u << 10)); // 512 KB (atomic; zeroed by k_prep)
    uint32_t* colbits = (uint32_t*)(ws + (528u << 10));// 256 B (fully written)
    float*    topo    = (float*)(ws + (532u << 10));   // 32 KB (fully written)

    k_prep<<<1668, 256, 0, stream>>>(x, xbf, Wq, Wk, Wv, Wo, wt, (float4*)ws, Wg1, y);
    k_edges<<<256, 256, 0, stream>>>(ei, cursor, scol, ebits);
    k_gnn_qkv<<<3584, 256, 0, stream>>>(y, cursor, scol, bg1, Wg2, bg2, topo,
                                        xbf, wt, bq, bk, bv, qbf, kt, vt3);
    k_topk<<<dim3(8, 4), 256, 0, stream>>>(topo, colbits);
    k_attn_mask<<<2048 + (32768 - LIVE_ROWS), 256, 0, stream>>>(qbf, kt, vt3, ebits, colbits,
                                                                po, pl, mask4);
    k_fin<<<1024, 256, 0, stream>>>(po, pl, aoutb);
    k_gemm_o<<<512, 256, 0, stream>>>(aoutb, wt + 196608, bo, out0);
    k_mask4b<<<LIVE_ROWS, 256, 0, stream>>>(ebits, colbits, mask4);
}

// Round 14
// 302.285 us; speedup vs baseline: 1.1546x; 1.1546x over previous
//
#include <hip/hip_runtime.h>
#include <hip/hip_bf16.h>
#include <stdint.h>

#define NTOK 2048
#define NB 4
#define DM 256
#define HD 64
#define NE 65536
#define SCAP 128
#define NKSL 4            // K-slices for attention partials

typedef __bf16 bf16x8 __attribute__((ext_vector_type(8)));
typedef float f32x4 __attribute__((ext_vector_type(4)));

#define MFMA16 __builtin_amdgcn_mfma_f32_16x16x32_bf16

__device__ __forceinline__ unsigned short f2bf(float f) {
    union { float f; uint32_t u; } v; v.f = f;
    return (unsigned short)((v.u + 0x7fffu + ((v.u >> 16) & 1u)) >> 16);
}

// ---------------- F0: ws-zero + W^T + fused {x cast + y = x@Wg1} ----------------
__global__ __launch_bounds__(256) void k_prep(const float* __restrict__ x,
                       unsigned short* __restrict__ xb,
                       const float* __restrict__ W0, const float* __restrict__ W1,
                       const float* __restrict__ W2, const float* __restrict__ W3,
                       unsigned short* __restrict__ WT, float4* __restrict__ wsz,
                       const float* __restrict__ Wg1, float* __restrict__ y) {
    __shared__ float xs[16][256];
    int bid = blockIdx.x, t = threadIdx.x;
    if (bid < 132) {
        wsz[bid * 256 + t] = float4{0.f, 0.f, 0.f, 0.f};
    } else if (bid < 1156) {
        int b2 = bid - 132;                        // [0,1024)
        int sel = b2 >> 8;
        const float* W = sel == 0 ? W0 : sel == 1 ? W1 : sel == 2 ? W2 : W3;
        int e = (b2 & 255) * 256 + t;              // e = n*256 + k
        int n = e >> 8, k = e & 255;
        WT[sel * 65536 + e] = f2bf(W[k * 256 + n]);
    } else {
        // 16 tokens per block: load x tile, emit bf16 cast, compute y = x@Wg1
        int m0 = (bid - 1156) * 16;
        #pragma unroll
        for (int j = 0; j < 16; ++j) {
            float v = x[(size_t)(m0 + j) * DM + t];
            xs[j][t] = v;
            xb[(size_t)(m0 + j) * DM + t] = f2bf(v);
        }
        __syncthreads();
        int c = t & 127, g = t >> 7;               // g: token half (8 tokens)
        float acc[8] = {0.f, 0.f, 0.f, 0.f, 0.f, 0.f, 0.f, 0.f};
        const float* xr = &xs[g * 8][0];
        #pragma unroll 4
        for (int r = 0; r < DM; ++r) {
            float w = Wg1[r * 128 + c];
            #pragma unroll
            for (int j = 0; j < 8; ++j) acc[j] += xr[j * 256 + r] * w;
        }
        #pragma unroll
        for (int j = 0; j < 8; ++j) y[(size_t)(m0 + g * 8 + j) * 128 + c] = acc[j];
    }
}

// ---------------- edges: fused count + bucket-scatter + bitmap ----------------
__global__ void k_edges(const int* __restrict__ ei, uint32_t* __restrict__ cursor,
                        uint32_t* __restrict__ scol, uint32_t* __restrict__ ebits) {
    int e = blockIdx.x * 256 + threadIdx.x;
    int r = ei[e];
    int c = ei[NE + e];
    uint32_t slot = atomicAdd(&cursor[r], 1u);
    if (slot < SCAP) scol[r * SCAP + slot] = (uint32_t)c;
    atomicOr(&ebits[r * 64 + (c >> 5)], 1u << (c & 31));
}

// ---------------- fused: GNN-on-y (blocks [0,2048)) + QKV GEMM ([2048,3584)) ----------------
// K out: KT[bh][nb=tok>>4][nw=tok&15][d]   V out: VT3[bh][nb=tok>>5][d][nw=tok&31]
__global__ __launch_bounds__(256) void k_gnn_qkv(
    const float* __restrict__ y, const uint32_t* __restrict__ cursor,
    const uint32_t* __restrict__ scol,
    const float* __restrict__ bg1, const float* __restrict__ Wg2,
    const float* __restrict__ bg2, float* __restrict__ topo,
    const unsigned short* __restrict__ xbf, const unsigned short* __restrict__ WT,
    const float* __restrict__ bq, const float* __restrict__ bk, const float* __restrict__ bv,
    unsigned short* __restrict__ qo, unsigned short* __restrict__ kt,
    unsigned short* __restrict__ vt3) {
    int bid = blockIdx.x, t = threadIdx.x;
    if (bid < 2048) {
        // gather y[col] (128 f32 per batch), f64 accumulate; batches (bp, bp+2)
        int i = bid;
        int d = t & 127, bp = t >> 7;
        uint32_t cnt = cursor[i]; if (cnt > SCAP) cnt = SCAP;
        const uint32_t* sc = scol + i * SCAP;
        const float* yA = y + (size_t)(bp * NTOK) * 128 + d;        // batch bp
        const float* yB = y + (size_t)((bp + 2) * NTOK) * 128 + d;  // batch bp+2
        double A0 = 0, A1 = 0, A2 = 0, A3 = 0;
        double B0 = 0, B1 = 0, B2 = 0, B3 = 0;
        uint32_t e = 0;
        for (; e + 3 < cnt; e += 4) {
            int c0 = sc[e] << 7, c1 = sc[e + 1] << 7;
            int c2 = sc[e + 2] << 7, c3 = sc[e + 3] << 7;
            A0 += (double)yA[c0]; A1 += (double)yA[c1];
            A2 += (double)yA[c2]; A3 += (double)yA[c3];
            B0 += (double)yB[c0]; B1 += (double)yB[c1];
            B2 += (double)yB[c2]; B3 += (double)yB[c3];
        }
        for (; e < cnt; ++e) {
            int c0 = sc[e] << 7;
            A0 += (double)yA[c0];
            B0 += (double)yB[c0];
        }
        double hA = (A0 + A1) + (A2 + A3) + (double)bg1[d];
        double hB = (B0 + B1) + (B2 + B3) + (double)bg1[d];
        double w2 = (double)Wg2[d];
        double vA = (hA > 0 ? hA : 0.0) * w2;   // batch bp
        double vB = (hB > 0 ? hB : 0.0) * w2;   // batch bp+2
        #pragma unroll
        for (int s = 32; s >= 1; s >>= 1) {
            vA += __shfl_xor(vA, s);
            vB += __shfl_xor(vB, s);
        }
        __shared__ double red[4][2];
        int wid = t >> 6;
        if ((t & 63) == 0) { red[wid][0] = vA; red[wid][1] = vB; }
        __syncthreads();
        if (t == 0) {
            double bb = (double)bg2[0];
            topo[0 * NTOK + i] = (float)(red[0][0] + red[1][0] + bb);
            topo[2 * NTOK + i] = (float)(red[0][1] + red[1][1] + bb);
            topo[1 * NTOK + i] = (float)(red[2][0] + red[3][0] + bb);
            topo[3 * NTOK + i] = (float)(red[2][1] + red[3][1] + bb);
        }
    } else {
        int b2 = bid - 2048;
        int z = b2 >> 9, r2 = b2 & 511;
        const unsigned short* W = WT + z * 65536;
        const float* bias = z == 0 ? bq : z == 1 ? bk : bv;

        int lane = t & 63, w = t >> 6;
        int l15 = lane & 15, grp = lane >> 4;
        int mbase = (r2 & 127) * 64 + w * 16;
        int nbase = (r2 >> 7) * 64;
        f32x4 acc0 = {0,0,0,0}, acc1 = {0,0,0,0}, acc2 = {0,0,0,0}, acc3 = {0,0,0,0};
        const unsigned short* ap = xbf + (size_t)(mbase + l15) * DM + grp * 8;
        const unsigned short* bp2 = W + (size_t)(nbase + l15) * DM + grp * 8;
        #pragma unroll
        for (int k0 = 0; k0 < DM; k0 += 32) {
            bf16x8 af = *(const bf16x8*)(ap + k0);
            acc0 = MFMA16(af, *(const bf16x8*)(bp2 + k0), acc0, 0, 0, 0);
            acc1 = MFMA16(af, *(const bf16x8*)(bp2 + 16 * DM + k0), acc1, 0, 0, 0);
            acc2 = MFMA16(af, *(const bf16x8*)(bp2 + 32 * DM + k0), acc2, 0, 0, 0);
            acc3 = MFMA16(af, *(const bf16x8*)(bp2 + 48 * DM + k0), acc3, 0, 0, 0);
        }
        f32x4 accs[4] = {acc0, acc1, acc2, acc3};
        #pragma unroll
        for (int ct = 0; ct < 4; ++ct) {
            #pragma unroll
            for (int r = 0; r < 4; ++r) {
                int m = mbase + grp * 4 + r;            // token (w/in 8192)
                int n = nbase + ct * 16 + l15;          // feature (h*64+d)
                float v = accs[ct][r] + bias[n];
                if (z == 0) {
                    qo[(size_t)m * DM + n] = f2bf(v);
                } else {
                    int b = m >> 11, tok = m & 2047, h = n >> 6, d = n & 63;
                    int bh = (b << 2) + h;
                    if (z == 1) {
                        kt[(size_t)bh * 131072 + (tok >> 4) * 1024 + (tok & 15) * 64 + d] = f2bf(v);
                    } else {
                        vt3[(size_t)bh * 131072 + (tok >> 5) * 2048 + d * 32 + (tok & 31)] = f2bf(v);
                    }
                }
            }
        }
    }
}

// ---------------- top-k column mask (stable tie-break = lax.top_k), float4 scan ----------------
__global__ __launch_bounds__(256) void k_topk(const float* __restrict__ topo,
                                              uint32_t* __restrict__ colbits) {
    int b = blockIdx.y, t = threadIdx.x;
    int i = blockIdx.x * 256 + t;
    __shared__ float4 sc4[NTOK / 4];
    const float4* tp = (const float4*)(topo + b * NTOK);
    for (int j = t; j < NTOK / 4; j += 256) sc4[j] = tp[j];
    __syncthreads();
    float si = ((const float*)sc4)[i];
    int rank = 0;
    #pragma unroll 2
    for (int jj = 0; jj < NTOK / 4; ++jj) {
        float4 v = sc4[jj];
        int j0 = jj * 4;
        rank += (v.x > si) || (v.x == si && (j0    ) < i);
        rank += (v.y > si) || (v.y == si && (j0 + 1) < i);
        rank += (v.z > si) || (v.z == si && (j0 + 2) < i);
        rank += (v.w > si) || (v.w == si && (j0 + 3) < i);
    }
    unsigned long long m = __ballot(rank < 1024);
    int lane = t & 63;
    if (lane == 0)       colbits[b * 64 + (i >> 5)] = (uint32_t)m;
    else if (lane == 32) colbits[b * 64 + (i >> 5)] = (uint32_t)(m >> 32);
}

// ---------------- attention partials, coalesced KT/VT3 layouts ----------------
// Fixed-shift softmax: p = exp(s - 8); slices combine additively.
__global__ __launch_bounds__(256) void k_attn_part(const unsigned short* __restrict__ Q,
                                                   const unsigned short* __restrict__ KT,
                                                   const unsigned short* __restrict__ VT3,
                                                   const uint32_t* __restrict__ ebits,
                                                   const uint32_t* __restrict__ colbits,
                                                   float* __restrict__ po,
                                                   float* __restrict__ pl) {
    int bid = blockIdx.x;
    int lane = threadIdx.x & 63, w = threadIdx.x >> 6;
    int l15 = lane & 15, grp = lane >> 4;
    int ks = bid >> 9;                  // K-slice 0..NKSL-1
    int bh = (bid >> 5) & 15, b = bh >> 2, h = bh & 3;
    int q = (bid & 31) * 64 + w * 16 + l15;

    const unsigned short* qp = Q + (size_t)(b * NTOK + q) * DM + h * HD + grp * 8;
    bf16x8 qf0 = *(const bf16x8*)(qp);
    bf16x8 qf1 = *(const bf16x8*)(qp + 32);
    const unsigned short* kbase = KT + (size_t)bh * 131072 + l15 * 64 + grp * 8;
    const unsigned short* vbase = VT3 + (size_t)bh * 131072 + l15 * 32 + grp * 8;
    const uint32_t* eb = ebits + q * 64;
    const uint32_t* cbp = colbits + b * 64;

    f32x4 o0 = {0,0,0,0}, o1 = {0,0,0,0}, o2 = {0,0,0,0}, o3 = {0,0,0,0};
    float psum = 0.f;

    int kb0 = ks * (NTOK / NKSL);
    for (int kb = kb0; kb < kb0 + NTOK / NKSL; kb += 32) {
        const unsigned short* kp0 = kbase + (kb >> 4) * 1024;
        f32x4 st0 = {0,0,0,0}, st1 = {0,0,0,0};
        st0 = MFMA16(*(const bf16x8*)(kp0), qf0, st0, 0, 0, 0);
        st0 = MFMA16(*(const bf16x8*)(kp0 + 32), qf1, st0, 0, 0, 0);
        st1 = MFMA16(*(const bf16x8*)(kp0 + 1024), qf0, st1, 0, 0, 0);
        st1 = MFMA16(*(const bf16x8*)(kp0 + 1024 + 32), qf1, st1, 0, 0, 0);

        uint32_t mw = eb[kb >> 5] | cbp[kb >> 5];
        float p[8];
        #pragma unroll
        for (int r = 0; r < 4; ++r) {
            int p0 = grp * 4 + r;
            p[r]     = ((mw >> p0) & 1u)        ? __expf(st0[r] * 0.125f - 8.0f) : 0.f;
            p[4 + r] = ((mw >> (16 + p0)) & 1u) ? __expf(st1[r] * 0.125f - 8.0f) : 0.f;
        }
        #pragma unroll
        for (int j = 0; j < 8; ++j) psum += p[j];

        uint32_t pk00, pk01, pk10, pk11;
        asm("v_cvt_pk_bf16_f32 %0, %1, %2" : "=v"(pk00) : "v"(p[0]), "v"(p[1]));
        asm("v_cvt_pk_bf16_f32 %0, %1, %2" : "=v"(pk01) : "v"(p[2]), "v"(p[3]));
        asm("v_cvt_pk_bf16_f32 %0, %1, %2" : "=v"(pk10) : "v"(p[4]), "v"(p[5]));
        asm("v_cvt_pk_bf16_f32 %0, %1, %2" : "=v"(pk11) : "v"(p[6]), "v"(p[7]));
        union { uint32_t u[4]; bf16x8 v; } pf;
        #pragma unroll
        for (int wi = 0; wi < 4; ++wi) {
            int src = (((grp * 2 + (wi >> 1)) & 3) << 4) | l15;
            uint32_t lo = (uint32_t)__shfl((int)((wi & 1) ? pk01 : pk00), src);
            uint32_t hi = (uint32_t)__shfl((int)((wi & 1) ? pk11 : pk10), src);
            pf.u[wi] = (lane >= 32) ? hi : lo;
        }

        const unsigned short* vk = vbase + (kb >> 5) * 2048;
        o0 = MFMA16(*(const bf16x8*)(vk),            pf.v, o0, 0, 0, 0);
        o1 = MFMA16(*(const bf16x8*)(vk + 16 * 32),  pf.v, o1, 0, 0, 0);
        o2 = MFMA16(*(const bf16x8*)(vk + 32 * 32),  pf.v, o2, 0, 0, 0);
        o3 = MFMA16(*(const bf16x8*)(vk + 48 * 32),  pf.v, o3, 0, 0, 0);
    }
    psum += __shfl_xor(psum, 16);
    psum += __shfl_xor(psum, 32);

    float* pb = po + (((size_t)(ks * 16 + bh) * NTOK + q) * HD);
    *(f32x4*)(pb + 0 * 16 + grp * 4) = o0;
    *(f32x4*)(pb + 1 * 16 + grp * 4) = o1;
    *(f32x4*)(pb + 2 * 16 + grp * 4) = o2;
    *(f32x4*)(pb + 3 * 16 + grp * 4) = o3;
    if (grp == 0) pl[(size_t)(ks * 16 + bh) * NTOK + q] = psum;
}

// ---------------- combine K-slice partials -> normalized bf16 attention out ----------------
__global__ __launch_bounds__(256) void k_fin(const float* __restrict__ po,
                                             const float* __restrict__ pl,
                                             unsigned short* __restrict__ aoutb) {
    const size_t SL = (size_t)16 * NTOK * HD;   // po slice stride
    const size_t SLP = (size_t)16 * NTOK;       // pl slice stride
    int tid = blockIdx.x * 256 + threadIdx.x;   // 262144 total
    int dc = tid & 7;
    int q = (tid >> 3) & 2047;
    int bh = tid >> 14;
    size_t rb = ((size_t)bh * NTOK + q) * HD + dc * 8;
    float4 s0 = *(const float4*)(po + rb);
    float4 s1 = *(const float4*)(po + rb + 4);
    #pragma unroll
    for (int ks = 1; ks < NKSL; ++ks) {
        float4 a = *(const float4*)(po + ks * SL + rb);
        float4 c = *(const float4*)(po + ks * SL + rb + 4);
        s0.x += a.x; s0.y += a.y; s0.z += a.z; s0.w += a.w;
        s1.x += c.x; s1.y += c.y; s1.z += c.z; s1.w += c.w;
    }
    float l = 0.f;
    #pragma unroll
    for (int ks = 0; ks < NKSL; ++ks) l += pl[ks * SLP + (size_t)bh * NTOK + q];
    float inv = 1.f / l;
    int b = bh >> 2, h = bh & 3;
    union { ushort4 u4[2]; uint4 v; } out;
    out.u4[0].x = f2bf(s0.x * inv); out.u4[0].y = f2bf(s0.y * inv);
    out.u4[0].z = f2bf(s0.z * inv); out.u4[0].w = f2bf(s0.w * inv);
    out.u4[1].x = f2bf(s1.x * inv); out.u4[1].y = f2bf(s1.y * inv);
    out.u4[1].z = f2bf(s1.z * inv); out.u4[1].w = f2bf(s1.w * inv);
    *(uint4*)(aoutb + ((size_t)(b * NTOK + q) * DM) + h * HD + dc * 8) = out.v;
}

// ---------------- mask4 quad-row body: compute row (b,i) once, store to 4 heads ----------------
__device__ __forceinline__ void mask_quad(int idx, const uint32_t* __restrict__ eb,
                                          const uint32_t* __restrict__ cb,
                                          float* __restrict__ mout) {
    // idx in [0, 2097152): b = idx>>19, i = (idx>>8)&2047, j = (idx&255)*8
    int b = idx >> 19;
    int rem = idx & 524287;
    int i = rem >> 8;
    int j = (rem & 255) << 3;
    uint32_t mw = eb[i * 64 + (j >> 5)] | cb[b * 64 + (j >> 5)];
    int sh = j & 31;
    float4 v0, v1;
    v0.x = ((mw >> sh) & 1u) ? 1.f : 0.f;
    v0.y = ((mw >> (sh + 1)) & 1u) ? 1.f : 0.f;
    v0.z = ((mw >> (sh + 2)) & 1u) ? 1.f : 0.f;
    v0.w = ((mw >> (sh + 3)) & 1u) ? 1.f : 0.f;
    v1.x = ((mw >> (sh + 4)) & 1u) ? 1.f : 0.f;
    v1.y = ((mw >> (sh + 5)) & 1u) ? 1.f : 0.f;
    v1.z = ((mw >> (sh + 6)) & 1u) ? 1.f : 0.f;
    v1.w = ((mw >> (sh + 7)) & 1u) ? 1.f : 0.f;
    size_t base = (((size_t)b * 4) * NTOK + i) * NTOK + j;
    #pragma unroll
    for (int hh = 0; hh < 4; ++hh) {
        float* p = mout + base + (size_t)hh * NTOK * NTOK;
        *(float4*)p = v0;
        *(float4*)(p + 4) = v1;
    }
}

// ---------------- mask4 writer (Path B: runs LAST; overwrites all scratch) ----------------
__global__ void k_mask4(const uint32_t* __restrict__ ebits, const uint32_t* __restrict__ colbits,
                        float* __restrict__ mout) {
    mask_quad(blockIdx.x * 256 + threadIdx.x, ebits, colbits, mout);
}

// ---------------- output projection GEMM body ----------------
__device__ __forceinline__ void gemm_o_body(int bid, const unsigned short* __restrict__ A,
                                            const unsigned short* __restrict__ WT,
                                            const float* __restrict__ bias,
                                            float* __restrict__ out) {
    int lane = threadIdx.x & 63, w = threadIdx.x >> 6;
    int l15 = lane & 15, grp = lane >> 4;
    int mbase = (bid & 127) * 64 + w * 16;
    int nbase = (bid >> 7) * 64;
    f32x4 acc0 = {0,0,0,0}, acc1 = {0,0,0,0}, acc2 = {0,0,0,0}, acc3 = {0,0,0,0};
    const unsigned short* ap = A + (size_t)(mbase + l15) * DM + grp * 8;
    const unsigned short* bp = WT + (size_t)(nbase + l15) * DM + grp * 8;
    #pragma unroll
    for (int k0 = 0; k0 < DM; k0 += 32) {
        bf16x8 af = *(const bf16x8*)(ap + k0);
        acc0 = MFMA16(af, *(const bf16x8*)(bp + k0), acc0, 0, 0, 0);
        acc1 = MFMA16(af, *(const bf16x8*)(bp + 16 * DM + k0), acc1, 0, 0, 0);
        acc2 = MFMA16(af, *(const bf16x8*)(bp + 32 * DM + k0), acc2, 0, 0, 0);
        acc3 = MFMA16(af, *(const bf16x8*)(bp + 48 * DM + k0), acc3, 0, 0, 0);
    }
    f32x4 accs[4] = {acc0, acc1, acc2, acc3};
    #pragma unroll
    for (int ct = 0; ct < 4; ++ct) {
        #pragma unroll
        for (int r = 0; r < 4; ++r) {
            int m = mbase + grp * 4 + r;
            int n = nbase + ct * 16 + l15;
            out[(size_t)m * DM + n] = accs[ct][r] + bias[n];
        }
    }
}

__global__ __launch_bounds__(256) void k_gemm_o(const unsigned short* __restrict__ A,
                                                const unsigned short* __restrict__ WT,
                                                const float* __restrict__ bias,
                                                float* __restrict__ out) {
    gemm_o_body(blockIdx.x, A, WT, bias, out);
}

// ---------------- Path A: fused output GEMM (blocks [0,512)) + full mask4 write ----------------
__global__ __launch_bounds__(256) void k_gemm_mask(const unsigned short* __restrict__ A,
                                                   const unsigned short* __restrict__ WT,
                                                   const float* __restrict__ bias,
                                                   float* __restrict__ out,
                                                   const uint32_t* __restrict__ ebits,
                                                   const uint32_t* __restrict__ colbits,
                                                   float* __restrict__ mout) {
    int bid = blockIdx.x;
    if (bid < 512) {
        gemm_o_body(bid, A, WT, bias, out);
    } else {
        mask_quad((bid - 512) * 256 + threadIdx.x, ebits, colbits, mout);
    }
}

extern "C" void kernel_launch(void* const* d_in, const int* in_sizes, int n_in,
                              void* d_out, int out_size, void* d_ws, size_t ws_size,
                              hipStream_t stream) {
    const float* x   = (const float*)d_in[0];
    const int*   ei  = (const int*)d_in[1];          // int64 in reference -> int32 here
    const float* Wq  = (const float*)d_in[2];
    const float* bq  = (const float*)d_in[3];
    const float* Wk  = (const float*)d_in[4];
    const float* bk  = (const float*)d_in[5];
    const float* Wv  = (const float*)d_in[6];
    const float* bv  = (const float*)d_in[7];
    const float* Wo  = (const float*)d_in[8];
    const float* bo  = (const float*)d_in[9];
    const float* Wg1 = (const float*)d_in[10];
    const float* bg1 = (const float*)d_in[11];
    const float* Wg2 = (const float*)d_in[12];
    const float* bg2 = (const float*)d_in[13];

    float* out0  = (float*)d_out;
    float* mask4 = out0 + (size_t)NB * NTOK * DM;

    // Small scratch in d_ws (always)
    uint8_t* ws = (uint8_t*)d_ws;
    uint32_t* cursor  = (uint32_t*)(ws);               // 8 KB  (atomic; zeroed by k_prep)
    uint32_t* ebits   = (uint32_t*)(ws + (16u << 10)); // 512 KB (atomic; zeroed by k_prep)
    uint32_t* colbits = (uint32_t*)(ws + (528u << 10));// 256 B (fully written)
    float*    topo    = (float*)(ws + (532u << 10));   // 32 KB (fully written)

    bool big_ws = ws_size >= (62ull << 20);

    unsigned short *qbf, *kt, *vt3, *wt, *aoutb, *xbf;
    uint32_t* scol; float *y, *po, *pl;
    if (big_ws) {
        // Path A: all large scratch in d_ws; mask4 region written exactly once.
        uint8_t* b0 = ws + (1u << 20);
        qbf   = (unsigned short*)(b0);
        kt    = (unsigned short*)(b0 + (4u  << 20));
        vt3   = (unsigned short*)(b0 + (8u  << 20));
        wt    = (unsigned short*)(b0 + (12u << 20));
        aoutb = (unsigned short*)(b0 + (12u << 20) + (512u << 10));
        scol  = (uint32_t*)      (b0 + (16u << 20) + (512u << 10));
        xbf   = (unsigned short*)(b0 + (17u << 20) + (512u << 10));
        y     = (float*)         (b0 + (21u << 20) + (512u << 10));
        po    = (float*)         (b0 + (25u << 20) + (512u << 10));
        pl    = (float*)         (b0 + (57u << 20) + (512u << 10)); // ends 58.5 MB
    } else {
        // Path B: large scratch in mask4 region; k_mask4 runs last, overwrites all.
        uint8_t* big = (uint8_t*)mask4;
        qbf   = (unsigned short*)(big);
        kt    = (unsigned short*)(big + (4u  << 20));
        vt3   = (unsigned short*)(big + (8u  << 20));
        wt    = (unsigned short*)(big + (12u << 20));
        aoutb = (unsigned short*)(big + (12u << 20) + (512u << 10));
        scol  = (uint32_t*)      (big + (16u << 20) + (512u << 10));
        xbf   = (unsigned short*)(big + (17u << 20) + (512u << 10));
        y     = (float*)         (big + (21u << 20) + (512u << 10));
        po    = (float*)         (big + (25u << 20) + (512u << 10));
        pl    = (float*)         (big + (57u << 20) + (512u << 10));
    }

    k_prep<<<1668, 256, 0, stream>>>(x, xbf, Wq, Wk, Wv, Wo, wt, (float4*)ws, Wg1, y);
    k_edges<<<256, 256, 0, stream>>>(ei, cursor, scol, ebits);
    k_gnn_qkv<<<3584, 256, 0, stream>>>(y, cursor, scol, bg1, Wg2, bg2, topo,
                                        xbf, wt, bq, bk, bv, qbf, kt, vt3);
    k_topk<<<dim3(8, 4), 256, 0, stream>>>(topo, colbits);
    k_attn_part<<<NKSL * 512, 256, 0, stream>>>(qbf, kt, vt3, ebits, colbits, po, pl);
    k_fin<<<1024, 256, 0, stream>>>(po, pl, aoutb);
    if (big_ws) {
        k_gemm_mask<<<512 + 8192, 256, 0, stream>>>(aoutb, wt + 196608, bo, out0,
                                                    ebits, colbits, mask4);
    } else {
        k_gemm_o<<<512, 256, 0, stream>>>(aoutb, wt + 196608, bo, out0);
        k_mask4<<<8192, 256, 0, stream>>>(ebits, colbits, mask4);
    }
}

// Round 15
// 251.213 us; speedup vs baseline: 1.3894x; 1.2033x over previous
//
#include <hip/hip_runtime.h>
#include <hip/hip_bf16.h>
#include <stdint.h>

#define NTOK 2048
#define NB 4
#define DM 256
#define HD 64
#define NE 65536
#define SCAP 128
#define NKSL 4            // K-slices for attention partials

typedef __bf16 bf16x8 __attribute__((ext_vector_type(8)));
typedef float f32x4 __attribute__((ext_vector_type(4)));

#define MFMA16 __builtin_amdgcn_mfma_f32_16x16x32_bf16

__device__ __forceinline__ unsigned short f2bf(float f) {
    union { float f; uint32_t u; } v; v.f = f;
    return (unsigned short)((v.u + 0x7fffu + ((v.u >> 16) & 1u)) >> 16);
}

// ---------------- F0: ws-zero + W^T + fused {x cast + y = x@Wg1} ----------------
__global__ __launch_bounds__(256) void k_prep(const float* __restrict__ x,
                       unsigned short* __restrict__ xb,
                       const float* __restrict__ W0, const float* __restrict__ W1,
                       const float* __restrict__ W2, const float* __restrict__ W3,
                       unsigned short* __restrict__ WT, float4* __restrict__ wsz,
                       const float* __restrict__ Wg1, float* __restrict__ y) {
    __shared__ float xs[16][256];
    int bid = blockIdx.x, t = threadIdx.x;
    if (bid < 132) {
        wsz[bid * 256 + t] = float4{0.f, 0.f, 0.f, 0.f};
    } else if (bid < 1156) {
        int b2 = bid - 132;                        // [0,1024)
        int sel = b2 >> 8;
        const float* W = sel == 0 ? W0 : sel == 1 ? W1 : sel == 2 ? W2 : W3;
        int e = (b2 & 255) * 256 + t;              // e = n*256 + k
        int n = e >> 8, k = e & 255;
        WT[sel * 65536 + e] = f2bf(W[k * 256 + n]);
    } else {
        // 16 tokens per block: load x tile, emit bf16 cast, compute y = x@Wg1
        int m0 = (bid - 1156) * 16;
        #pragma unroll
        for (int j = 0; j < 16; ++j) {
            float v = x[(size_t)(m0 + j) * DM + t];
            xs[j][t] = v;
            xb[(size_t)(m0 + j) * DM + t] = f2bf(v);
        }
        __syncthreads();
        int c = t & 127, g = t >> 7;               // g: token half (8 tokens)
        float acc[8] = {0.f, 0.f, 0.f, 0.f, 0.f, 0.f, 0.f, 0.f};
        const float* xr = &xs[g * 8][0];
        #pragma unroll 4
        for (int r = 0; r < DM; ++r) {
            float w = Wg1[r * 128 + c];
            #pragma unroll
            for (int j = 0; j < 8; ++j) acc[j] += xr[j * 256 + r] * w;
        }
        #pragma unroll
        for (int j = 0; j < 8; ++j) y[(size_t)(m0 + g * 8 + j) * 128 + c] = acc[j];
    }
}

// ---------------- edges: fused count + bucket-scatter + bitmap ----------------
__global__ void k_edges(const int* __restrict__ ei, uint32_t* __restrict__ cursor,
                        uint32_t* __restrict__ scol, uint32_t* __restrict__ ebits) {
    int e = blockIdx.x * 256 + threadIdx.x;
    int r = ei[e];
    int c = ei[NE + e];
    uint32_t slot = atomicAdd(&cursor[r], 1u);
    if (slot < SCAP) scol[r * SCAP + slot] = (uint32_t)c;
    atomicOr(&ebits[r * 64 + (c >> 5)], 1u << (c & 31));
}

// ---------------- fused: GNN-on-y (blocks [0,2048)) + QKV GEMM ([2048,3584)) ----------------
// K out: KT[bh][nb=tok>>4][nw=tok&15][d]   V out: VT3[bh][nb=tok>>5][d][nw=tok&31]
__global__ __launch_bounds__(256) void k_gnn_qkv(
    const float* __restrict__ y, const uint32_t* __restrict__ cursor,
    const uint32_t* __restrict__ scol,
    const float* __restrict__ bg1, const float* __restrict__ Wg2,
    const float* __restrict__ bg2, float* __restrict__ topo,
    const unsigned short* __restrict__ xbf, const unsigned short* __restrict__ WT,
    const float* __restrict__ bq, const float* __restrict__ bk, const float* __restrict__ bv,
    unsigned short* __restrict__ qo, unsigned short* __restrict__ kt,
    unsigned short* __restrict__ vt3) {
    int bid = blockIdx.x, t = threadIdx.x;
    if (bid < 2048) {
        // gather y[col] (128 f32 per batch), f64 accumulate; batches (bp, bp+2)
        int i = bid;
        int d = t & 127, bp = t >> 7;
        uint32_t cnt = cursor[i]; if (cnt > SCAP) cnt = SCAP;
        const uint32_t* sc = scol + i * SCAP;
        const float* yA = y + (size_t)(bp * NTOK) * 128 + d;        // batch bp
        const float* yB = y + (size_t)((bp + 2) * NTOK) * 128 + d;  // batch bp+2
        double A0 = 0, A1 = 0, A2 = 0, A3 = 0;
        double B0 = 0, B1 = 0, B2 = 0, B3 = 0;
        uint32_t e = 0;
        for (; e + 3 < cnt; e += 4) {
            int c0 = sc[e] << 7, c1 = sc[e + 1] << 7;
            int c2 = sc[e + 2] << 7, c3 = sc[e + 3] << 7;
            A0 += (double)yA[c0]; A1 += (double)yA[c1];
            A2 += (double)yA[c2]; A3 += (double)yA[c3];
            B0 += (double)yB[c0]; B1 += (double)yB[c1];
            B2 += (double)yB[c2]; B3 += (double)yB[c3];
        }
        for (; e < cnt; ++e) {
            int c0 = sc[e] << 7;
            A0 += (double)yA[c0];
            B0 += (double)yB[c0];
        }
        double hA = (A0 + A1) + (A2 + A3) + (double)bg1[d];
        double hB = (B0 + B1) + (B2 + B3) + (double)bg1[d];
        double w2 = (double)Wg2[d];
        double vA = (hA > 0 ? hA : 0.0) * w2;   // batch bp
        double vB = (hB > 0 ? hB : 0.0) * w2;   // batch bp+2
        #pragma unroll
        for (int s = 32; s >= 1; s >>= 1) {
            vA += __shfl_xor(vA, s);
            vB += __shfl_xor(vB, s);
        }
        __shared__ double red[4][2];
        int wid = t >> 6;
        if ((t & 63) == 0) { red[wid][0] = vA; red[wid][1] = vB; }
        __syncthreads();
        if (t == 0) {
            double bb = (double)bg2[0];
            topo[0 * NTOK + i] = (float)(red[0][0] + red[1][0] + bb);
            topo[2 * NTOK + i] = (float)(red[0][1] + red[1][1] + bb);
            topo[1 * NTOK + i] = (float)(red[2][0] + red[3][0] + bb);
            topo[3 * NTOK + i] = (float)(red[2][1] + red[3][1] + bb);
        }
    } else {
        int b2 = bid - 2048;
        int z = b2 >> 9, r2 = b2 & 511;
        const unsigned short* W = WT + z * 65536;
        const float* bias = z == 0 ? bq : z == 1 ? bk : bv;

        int lane = t & 63, w = t >> 6;
        int l15 = lane & 15, grp = lane >> 4;
        int mbase = (r2 & 127) * 64 + w * 16;
        int nbase = (r2 >> 7) * 64;
        f32x4 acc0 = {0,0,0,0}, acc1 = {0,0,0,0}, acc2 = {0,0,0,0}, acc3 = {0,0,0,0};
        const unsigned short* ap = xbf + (size_t)(mbase + l15) * DM + grp * 8;
        const unsigned short* bp2 = W + (size_t)(nbase + l15) * DM + grp * 8;
        #pragma unroll
        for (int k0 = 0; k0 < DM; k0 += 32) {
            bf16x8 af = *(const bf16x8*)(ap + k0);
            acc0 = MFMA16(af, *(const bf16x8*)(bp2 + k0), acc0, 0, 0, 0);
            acc1 = MFMA16(af, *(const bf16x8*)(bp2 + 16 * DM + k0), acc1, 0, 0, 0);
            acc2 = MFMA16(af, *(const bf16x8*)(bp2 + 32 * DM + k0), acc2, 0, 0, 0);
            acc3 = MFMA16(af, *(const bf16x8*)(bp2 + 48 * DM + k0), acc3, 0, 0, 0);
        }
        f32x4 accs[4] = {acc0, acc1, acc2, acc3};
        #pragma unroll
        for (int ct = 0; ct < 4; ++ct) {
            #pragma unroll
            for (int r = 0; r < 4; ++r) {
                int m = mbase + grp * 4 + r;            // token (w/in 8192)
                int n = nbase + ct * 16 + l15;          // feature (h*64+d)
                float v = accs[ct][r] + bias[n];
                if (z == 0) {
                    qo[(size_t)m * DM + n] = f2bf(v);
                } else {
                    int b = m >> 11, tok = m & 2047, h = n >> 6, d = n & 63;
                    int bh = (b << 2) + h;
                    if (z == 1) {
                        kt[(size_t)bh * 131072 + (tok >> 4) * 1024 + (tok & 15) * 64 + d] = f2bf(v);
                    } else {
                        vt3[(size_t)bh * 131072 + (tok >> 5) * 2048 + d * 32 + (tok & 31)] = f2bf(v);
                    }
                }
            }
        }
    }
}

// ---------------- top-k column mask (stable tie-break = lax.top_k), float4 scan ----------------
__global__ __launch_bounds__(256) void k_topk(const float* __restrict__ topo,
                                              uint32_t* __restrict__ colbits) {
    int b = blockIdx.y, t = threadIdx.x;
    int i = blockIdx.x * 256 + t;
    __shared__ float4 sc4[NTOK / 4];
    const float4* tp = (const float4*)(topo + b * NTOK);
    for (int j = t; j < NTOK / 4; j += 256) sc4[j] = tp[j];
    __syncthreads();
    float si = ((const float*)sc4)[i];
    int rank = 0;
    #pragma unroll 2
    for (int jj = 0; jj < NTOK / 4; ++jj) {
        float4 v = sc4[jj];
        int j0 = jj * 4;
        rank += (v.x > si) || (v.x == si && (j0    ) < i);
        rank += (v.y > si) || (v.y == si && (j0 + 1) < i);
        rank += (v.z > si) || (v.z == si && (j0 + 2) < i);
        rank += (v.w > si) || (v.w == si && (j0 + 3) < i);
    }
    unsigned long long m = __ballot(rank < 1024);
    int lane = t & 63;
    if (lane == 0)       colbits[b * 64 + (i >> 5)] = (uint32_t)m;
    else if (lane == 32) colbits[b * 64 + (i >> 5)] = (uint32_t)(m >> 32);
}

// ---------------- attention partials: LDS-staged K/V (XOR-swizzled), double-buffered ----------------
// Fixed-shift softmax: p = exp(s - 8); slices combine additively.
__global__ __launch_bounds__(256) void k_attn_part(const unsigned short* __restrict__ Q,
                                                   const unsigned short* __restrict__ KT,
                                                   const unsigned short* __restrict__ VT3,
                                                   const uint32_t* __restrict__ ebits,
                                                   const uint32_t* __restrict__ colbits,
                                                   float* __restrict__ po,
                                                   float* __restrict__ pl) {
    __shared__ unsigned short ksh[2][2048];   // 4 KB per buffer: 32 tok x 64 d
    __shared__ unsigned short vsh[2][2048];   // 4 KB per buffer: 64 d x 32 tok
    int bid = blockIdx.x;
    int t = threadIdx.x;
    int lane = t & 63, w = t >> 6;
    int l15 = lane & 15, grp = lane >> 4;
    int ks = bid >> 9;                  // K-slice 0..NKSL-1
    int bh = (bid >> 5) & 15, b = bh >> 2, h = bh & 3;
    int q = (bid & 31) * 64 + w * 16 + l15;

    const unsigned short* qp = Q + (size_t)(b * NTOK + q) * DM + h * HD + grp * 8;
    bf16x8 qf0 = *(const bf16x8*)(qp);
    bf16x8 qf1 = *(const bf16x8*)(qp + 32);
    const unsigned short* Kt = KT + (size_t)bh * 131072;
    const unsigned short* Vt = VT3 + (size_t)bh * 131072;
    const uint32_t* eb = ebits + q * 64;
    const uint32_t* cbp = colbits + b * 64;

    int kb0 = ks * (NTOK / NKSL);

    // swizzled store offsets (bytes) for this thread's 16B chunk
    int kso = (t * 16) ^ (((t >> 3) & 7) << 4);   // K rows are 128 B
    int vso = (t * 16) ^ (((t >> 2) & 7) << 4);   // V rows are 64 B
    // swizzled read offsets: all rows used by this lane have row&7 == l15&7
    int swz = (l15 & 7) << 4;

    // stage iteration 0
    {
        uint4 kv = *(const uint4*)(Kt + (size_t)(kb0 >> 4) * 1024 + t * 8);
        *(uint4*)((char*)&ksh[0][0] + kso) = kv;
        uint4 vv = *(const uint4*)(Vt + (size_t)(kb0 >> 5) * 2048 + t * 8);
        *(uint4*)((char*)&vsh[0][0] + vso) = vv;
    }
    __syncthreads();

    f32x4 o0 = {0,0,0,0}, o1 = {0,0,0,0}, o2 = {0,0,0,0}, o3 = {0,0,0,0};
    float psum = 0.f;

    for (int it = 0; it < NTOK / NKSL / 32; ++it) {
        int buf = it & 1;
        if (it + 1 < NTOK / NKSL / 32) {
            int kb = kb0 + (it + 1) * 32;
            uint4 kv = *(const uint4*)(Kt + (size_t)(kb >> 4) * 1024 + t * 8);
            *(uint4*)((char*)&ksh[buf ^ 1][0] + kso) = kv;
            uint4 vv = *(const uint4*)(Vt + (size_t)(kb >> 5) * 2048 + t * 8);
            *(uint4*)((char*)&vsh[buf ^ 1][0] + vso) = vv;
        }
        int kb = kb0 + it * 32;
        const char* kp = (const char*)&ksh[buf][0];
        const char* vp = (const char*)&vsh[buf][0];

        f32x4 st0 = {0,0,0,0}, st1 = {0,0,0,0};
        st0 = MFMA16(*(const bf16x8*)(kp + ((l15 * 128 + grp * 16) ^ swz)),        qf0, st0, 0, 0, 0);
        st0 = MFMA16(*(const bf16x8*)(kp + ((l15 * 128 + 64 + grp * 16) ^ swz)),   qf1, st0, 0, 0, 0);
        st1 = MFMA16(*(const bf16x8*)(kp + (((16 + l15) * 128 + grp * 16) ^ swz)), qf0, st1, 0, 0, 0);
        st1 = MFMA16(*(const bf16x8*)(kp + (((16 + l15) * 128 + 64 + grp * 16) ^ swz)), qf1, st1, 0, 0, 0);

        uint32_t mw = eb[kb >> 5] | cbp[kb >> 5];
        float p[8];
        #pragma unroll
        for (int r = 0; r < 4; ++r) {
            int p0 = grp * 4 + r;
            p[r]     = ((mw >> p0) & 1u)        ? __expf(st0[r] * 0.125f - 8.0f) : 0.f;
            p[4 + r] = ((mw >> (16 + p0)) & 1u) ? __expf(st1[r] * 0.125f - 8.0f) : 0.f;
        }
        #pragma unroll
        for (int j = 0; j < 8; ++j) psum += p[j];

        uint32_t pk00, pk01, pk10, pk11;
        asm("v_cvt_pk_bf16_f32 %0, %1, %2" : "=v"(pk00) : "v"(p[0]), "v"(p[1]));
        asm("v_cvt_pk_bf16_f32 %0, %1, %2" : "=v"(pk01) : "v"(p[2]), "v"(p[3]));
        asm("v_cvt_pk_bf16_f32 %0, %1, %2" : "=v"(pk10) : "v"(p[4]), "v"(p[5]));
        asm("v_cvt_pk_bf16_f32 %0, %1, %2" : "=v"(pk11) : "v"(p[6]), "v"(p[7]));
        union { uint32_t u[4]; bf16x8 v; } pf;
        #pragma unroll
        for (int wi = 0; wi < 4; ++wi) {
            int src = (((grp * 2 + (wi >> 1)) & 3) << 4) | l15;
            uint32_t lo = (uint32_t)__shfl((int)((wi & 1) ? pk01 : pk00), src);
            uint32_t hi = (uint32_t)__shfl((int)((wi & 1) ? pk11 : pk10), src);
            pf.u[wi] = (lane >= 32) ? hi : lo;
        }

        o0 = MFMA16(*(const bf16x8*)(vp + ((l15 * 64 + grp * 16) ^ swz)),          pf.v, o0, 0, 0, 0);
        o1 = MFMA16(*(const bf16x8*)(vp + (((16 + l15) * 64 + grp * 16) ^ swz)),   pf.v, o1, 0, 0, 0);
        o2 = MFMA16(*(const bf16x8*)(vp + (((32 + l15) * 64 + grp * 16) ^ swz)),   pf.v, o2, 0, 0, 0);
        o3 = MFMA16(*(const bf16x8*)(vp + (((48 + l15) * 64 + grp * 16) ^ swz)),   pf.v, o3, 0, 0, 0);
        __syncthreads();
    }
    psum += __shfl_xor(psum, 16);
    psum += __shfl_xor(psum, 32);

    float* pb = po + (((size_t)(ks * 16 + bh) * NTOK + q) * HD);
    *(f32x4*)(pb + 0 * 16 + grp * 4) = o0;
    *(f32x4*)(pb + 1 * 16 + grp * 4) = o1;
    *(f32x4*)(pb + 2 * 16 + grp * 4) = o2;
    *(f32x4*)(pb + 3 * 16 + grp * 4) = o3;
    if (grp == 0) pl[(size_t)(ks * 16 + bh) * NTOK + q] = psum;
}

// ---------------- combine K-slice partials -> normalized bf16 attention out ----------------
__global__ __launch_bounds__(256) void k_fin(const float* __restrict__ po,
                                             const float* __restrict__ pl,
                                             unsigned short* __restrict__ aoutb) {
    const size_t SL = (size_t)16 * NTOK * HD;   // po slice stride
    const size_t SLP = (size_t)16 * NTOK;       // pl slice stride
    int tid = blockIdx.x * 256 + threadIdx.x;   // 262144 total
    int dc = tid & 7;
    int q = (tid >> 3) & 2047;
    int bh = tid >> 14;
    size_t rb = ((size_t)bh * NTOK + q) * HD + dc * 8;
    float4 s0 = *(const float4*)(po + rb);
    float4 s1 = *(const float4*)(po + rb + 4);
    #pragma unroll
    for (int ks = 1; ks < NKSL; ++ks) {
        float4 a = *(const float4*)(po + ks * SL + rb);
        float4 c = *(const float4*)(po + ks * SL + rb + 4);
        s0.x += a.x; s0.y += a.y; s0.z += a.z; s0.w += a.w;
        s1.x += c.x; s1.y += c.y; s1.z += c.z; s1.w += c.w;
    }
    float l = 0.f;
    #pragma unroll
    for (int ks = 0; ks < NKSL; ++ks) l += pl[ks * SLP + (size_t)bh * NTOK + q];
    float inv = 1.f / l;
    int b = bh >> 2, h = bh & 3;
    union { ushort4 u4[2]; uint4 v; } out;
    out.u4[0].x = f2bf(s0.x * inv); out.u4[0].y = f2bf(s0.y * inv);
    out.u4[0].z = f2bf(s0.z * inv); out.u4[0].w = f2bf(s0.w * inv);
    out.u4[1].x = f2bf(s1.x * inv); out.u4[1].y = f2bf(s1.y * inv);
    out.u4[1].z = f2bf(s1.z * inv); out.u4[1].w = f2bf(s1.w * inv);
    *(uint4*)(aoutb + ((size_t)(b * NTOK + q) * DM) + h * HD + dc * 8) = out.v;
}

// ---------------- mask4 quad-row body: compute row (b,i) once, store to 4 heads ----------------
__device__ __forceinline__ void mask_quad(int idx, const uint32_t* __restrict__ eb,
                                          const uint32_t* __restrict__ cb,
                                          float* __restrict__ mout) {
    int b = idx >> 19;
    int rem = idx & 524287;
    int i = rem >> 8;
    int j = (rem & 255) << 3;
    uint32_t mw = eb[i * 64 + (j >> 5)] | cb[b * 64 + (j >> 5)];
    int sh = j & 31;
    float4 v0, v1;
    v0.x = ((mw >> sh) & 1u) ? 1.f : 0.f;
    v0.y = ((mw >> (sh + 1)) & 1u) ? 1.f : 0.f;
    v0.z = ((mw >> (sh + 2)) & 1u) ? 1.f : 0.f;
    v0.w = ((mw >> (sh + 3)) & 1u) ? 1.f : 0.f;
    v1.x = ((mw >> (sh + 4)) & 1u) ? 1.f : 0.f;
    v1.y = ((mw >> (sh + 5)) & 1u) ? 1.f : 0.f;
    v1.z = ((mw >> (sh + 6)) & 1u) ? 1.f : 0.f;
    v1.w = ((mw >> (sh + 7)) & 1u) ? 1.f : 0.f;
    size_t base = (((size_t)b * 4) * NTOK + i) * NTOK + j;
    #pragma unroll
    for (int hh = 0; hh < 4; ++hh) {
        float* p = mout + base + (size_t)hh * NTOK * NTOK;
        *(float4*)p = v0;
        *(float4*)(p + 4) = v1;
    }
}

// ---------------- mask4 writer (runs LAST; overwrites all scratch) ----------------
__global__ void k_mask4(const uint32_t* __restrict__ ebits, const uint32_t* __restrict__ colbits,
                        float* __restrict__ mout) {
    mask_quad(blockIdx.x * 256 + threadIdx.x, ebits, colbits, mout);
}

// ---------------- output projection GEMM (f32 out) ----------------
__global__ __launch_bounds__(256) void k_gemm_o(const unsigned short* __restrict__ A,
                                                const unsigned short* __restrict__ WT,
                                                const float* __restrict__ bias,
                                                float* __restrict__ out) {
    int bid = blockIdx.x;
    int lane = threadIdx.x & 63, w = threadIdx.x >> 6;
    int l15 = lane & 15, grp = lane >> 4;
    int mbase = (bid & 127) * 64 + w * 16;
    int nbase = (bid >> 7) * 64;
    f32x4 acc0 = {0,0,0,0}, acc1 = {0,0,0,0}, acc2 = {0,0,0,0}, acc3 = {0,0,0,0};
    const unsigned short* ap = A + (size_t)(mbase + l15) * DM + grp * 8;
    const unsigned short* bp = WT + (size_t)(nbase + l15) * DM + grp * 8;
    #pragma unroll
    for (int k0 = 0; k0 < DM; k0 += 32) {
        bf16x8 af = *(const bf16x8*)(ap + k0);
        acc0 = MFMA16(af, *(const bf16x8*)(bp + k0), acc0, 0, 0, 0);
        acc1 = MFMA16(af, *(const bf16x8*)(bp + 16 * DM + k0), acc1, 0, 0, 0);
        acc2 = MFMA16(af, *(const bf16x8*)(bp + 32 * DM + k0), acc2, 0, 0, 0);
        acc3 = MFMA16(af, *(const bf16x8*)(bp + 48 * DM + k0), acc3, 0, 0, 0);
    }
    f32x4 accs[4] = {acc0, acc1, acc2, acc3};
    #pragma unroll
    for (int ct = 0; ct < 4; ++ct) {
        #pragma unroll
        for (int r = 0; r < 4; ++r) {
            int m = mbase + grp * 4 + r;
            int n = nbase + ct * 16 + l15;
            out[(size_t)m * DM + n] = accs[ct][r] + bias[n];
        }
    }
}

extern "C" void kernel_launch(void* const* d_in, const int* in_sizes, int n_in,
                              void* d_out, int out_size, void* d_ws, size_t ws_size,
                              hipStream_t stream) {
    const float* x   = (const float*)d_in[0];
    const int*   ei  = (const int*)d_in[1];          // int64 in reference -> int32 here
    const float* Wq  = (const float*)d_in[2];
    const float* bq  = (const float*)d_in[3];
    const float* Wk  = (const float*)d_in[4];
    const float* bk  = (const float*)d_in[5];
    const float* Wv  = (const float*)d_in[6];
    const float* bv  = (const float*)d_in[7];
    const float* Wo  = (const float*)d_in[8];
    const float* bo  = (const float*)d_in[9];
    const float* Wg1 = (const float*)d_in[10];
    const float* bg1 = (const float*)d_in[11];
    const float* Wg2 = (const float*)d_in[12];
    const float* bg2 = (const float*)d_in[13];

    float* out0  = (float*)d_out;
    float* mask4 = out0 + (size_t)NB * NTOK * DM;

    // Large scratch in mask4 region; k_mask4 runs last and overwrites everything.
    uint8_t* big = (uint8_t*)mask4;
    unsigned short* qbf   = (unsigned short*)(big);
    unsigned short* kt    = (unsigned short*)(big + (4u  << 20));
    unsigned short* vt3   = (unsigned short*)(big + (8u  << 20));
    unsigned short* wt    = (unsigned short*)(big + (12u << 20));
    unsigned short* aoutb = (unsigned short*)(big + (12u << 20) + (512u << 10));
    uint32_t*       scol  = (uint32_t*)      (big + (16u << 20) + (512u << 10));
    unsigned short* xbf   = (unsigned short*)(big + (17u << 20) + (512u << 10));
    float*          y     = (float*)         (big + (21u << 20) + (512u << 10));
    float*          po    = (float*)         (big + (25u << 20) + (512u << 10));
    float*          pl    = (float*)         (big + (57u << 20) + (512u << 10));

    // Small scratch in d_ws
    uint8_t* ws = (uint8_t*)d_ws;
    uint32_t* cursor  = (uint32_t*)(ws);               // 8 KB  (atomic; zeroed by k_prep)
    uint32_t* ebits   = (uint32_t*)(ws + (16u << 10)); // 512 KB (atomic; zeroed by k_prep)
    uint32_t* colbits = (uint32_t*)(ws + (528u << 10));// 256 B (fully written)
    float*    topo    = (float*)(ws + (532u << 10));   // 32 KB (fully written)

    k_prep<<<1668, 256, 0, stream>>>(x, xbf, Wq, Wk, Wv, Wo, wt, (float4*)ws, Wg1, y);
    k_edges<<<256, 256, 0, stream>>>(ei, cursor, scol, ebits);
    k_gnn_qkv<<<3584, 256, 0, stream>>>(y, cursor, scol, bg1, Wg2, bg2, topo,
                                        xbf, wt, bq, bk, bv, qbf, kt, vt3);
    k_topk<<<dim3(8, 4), 256, 0, stream>>>(topo, colbits);
    k_attn_part<<<NKSL * 512, 256, 0, stream>>>(qbf, kt, vt3, ebits, colbits, po, pl);
    k_fin<<<1024, 256, 0, stream>>>(po, pl, aoutb);
    k_gemm_o<<<512, 256, 0, stream>>>(aoutb, wt + 196608, bo, out0);
    k_mask4<<<8192, 256, 0, stream>>>(ebits, colbits, mask4);
}

// Round 16
// 241.829 us; speedup vs baseline: 1.4433x; 1.0388x over previous
//
#include <hip/hip_runtime.h>
#include <hip/hip_bf16.h>
#include <stdint.h>

#define NTOK 2048
#define NB 4
#define DM 256
#define HD 64
#define NE 65536
#define SCAP 128
#define NKSL 4            // K-slices for attention partials
#define ROWS_A 2112       // rows [0,ROWS_A): qbf/kt/vt3/wt/aoutb (live until gemm) -> k_mask4b
#define ROWS_B 6272       // rows [ROWS_A,ROWS_B): po/pl (dead after fin) -> fused with gemm

typedef __bf16 bf16x8 __attribute__((ext_vector_type(8)));
typedef float f32x4 __attribute__((ext_vector_type(4)));

#define MFMA16 __builtin_amdgcn_mfma_f32_16x16x32_bf16

__device__ __forceinline__ unsigned short f2bf(float f) {
    union { float f; uint32_t u; } v; v.f = f;
    return (unsigned short)((v.u + 0x7fffu + ((v.u >> 16) & 1u)) >> 16);
}

// ---------------- F0: ws-zero + W^T + fused {x cast + y = x@Wg1} ----------------
__global__ __launch_bounds__(256) void k_prep(const float* __restrict__ x,
                       unsigned short* __restrict__ xb,
                       const float* __restrict__ W0, const float* __restrict__ W1,
                       const float* __restrict__ W2, const float* __restrict__ W3,
                       unsigned short* __restrict__ WT, float4* __restrict__ wsz,
                       const float* __restrict__ Wg1, float* __restrict__ y) {
    __shared__ float xs[16][256];
    int bid = blockIdx.x, t = threadIdx.x;
    if (bid < 132) {
        wsz[bid * 256 + t] = float4{0.f, 0.f, 0.f, 0.f};
    } else if (bid < 1156) {
        int b2 = bid - 132;                        // [0,1024)
        int sel = b2 >> 8;
        const float* W = sel == 0 ? W0 : sel == 1 ? W1 : sel == 2 ? W2 : W3;
        int e = (b2 & 255) * 256 + t;              // e = n*256 + k
        int n = e >> 8, k = e & 255;
        WT[sel * 65536 + e] = f2bf(W[k * 256 + n]);
    } else {
        int m0 = (bid - 1156) * 16;
        #pragma unroll
        for (int j = 0; j < 16; ++j) {
            float v = x[(size_t)(m0 + j) * DM + t];
            xs[j][t] = v;
            xb[(size_t)(m0 + j) * DM + t] = f2bf(v);
        }
        __syncthreads();
        int c = t & 127, g = t >> 7;               // g: token half (8 tokens)
        float acc[8] = {0.f, 0.f, 0.f, 0.f, 0.f, 0.f, 0.f, 0.f};
        const float* xr = &xs[g * 8][0];
        #pragma unroll 4
        for (int r = 0; r < DM; ++r) {
            float w = Wg1[r * 128 + c];
            #pragma unroll
            for (int j = 0; j < 8; ++j) acc[j] += xr[j * 256 + r] * w;
        }
        #pragma unroll
        for (int j = 0; j < 8; ++j) y[(size_t)(m0 + g * 8 + j) * 128 + c] = acc[j];
    }
}

// ---------------- edges: fused count + bucket-scatter + bitmap ----------------
__global__ void k_edges(const int* __restrict__ ei, uint32_t* __restrict__ cursor,
                        uint32_t* __restrict__ scol, uint32_t* __restrict__ ebits) {
    int e = blockIdx.x * 256 + threadIdx.x;
    int r = ei[e];
    int c = ei[NE + e];
    uint32_t slot = atomicAdd(&cursor[r], 1u);
    if (slot < SCAP) scol[r * SCAP + slot] = (uint32_t)c;
    atomicOr(&ebits[r * 64 + (c >> 5)], 1u << (c & 31));
}

// ---------------- fused: GNN-on-y (blocks [0,2048)) + QKV GEMM ([2048,3584)) ----------------
__global__ __launch_bounds__(256) void k_gnn_qkv(
    const float* __restrict__ y, const uint32_t* __restrict__ cursor,
    const uint32_t* __restrict__ scol,
    const float* __restrict__ bg1, const float* __restrict__ Wg2,
    const float* __restrict__ bg2, float* __restrict__ topo,
    const unsigned short* __restrict__ xbf, const unsigned short* __restrict__ WT,
    const float* __restrict__ bq, const float* __restrict__ bk, const float* __restrict__ bv,
    unsigned short* __restrict__ qo, unsigned short* __restrict__ kt,
    unsigned short* __restrict__ vt3) {
    int bid = blockIdx.x, t = threadIdx.x;
    if (bid < 2048) {
        int i = bid;
        int d = t & 127, bp = t >> 7;
        uint32_t cnt = cursor[i]; if (cnt > SCAP) cnt = SCAP;
        const uint32_t* sc = scol + i * SCAP;
        const float* yA = y + (size_t)(bp * NTOK) * 128 + d;
        const float* yB = y + (size_t)((bp + 2) * NTOK) * 128 + d;
        double A0 = 0, A1 = 0, A2 = 0, A3 = 0;
        double B0 = 0, B1 = 0, B2 = 0, B3 = 0;
        uint32_t e = 0;
        for (; e + 3 < cnt; e += 4) {
            int c0 = sc[e] << 7, c1 = sc[e + 1] << 7;
            int c2 = sc[e + 2] << 7, c3 = sc[e + 3] << 7;
            A0 += (double)yA[c0]; A1 += (double)yA[c1];
            A2 += (double)yA[c2]; A3 += (double)yA[c3];
            B0 += (double)yB[c0]; B1 += (double)yB[c1];
            B2 += (double)yB[c2]; B3 += (double)yB[c3];
        }
        for (; e < cnt; ++e) {
            int c0 = sc[e] << 7;
            A0 += (double)yA[c0];
            B0 += (double)yB[c0];
        }
        double hA = (A0 + A1) + (A2 + A3) + (double)bg1[d];
        double hB = (B0 + B1) + (B2 + B3) + (double)bg1[d];
        double w2 = (double)Wg2[d];
        double vA = (hA > 0 ? hA : 0.0) * w2;
        double vB = (hB > 0 ? hB : 0.0) * w2;
        #pragma unroll
        for (int s = 32; s >= 1; s >>= 1) {
            vA += __shfl_xor(vA, s);
            vB += __shfl_xor(vB, s);
        }
        __shared__ double red[4][2];
        int wid = t >> 6;
        if ((t & 63) == 0) { red[wid][0] = vA; red[wid][1] = vB; }
        __syncthreads();
        if (t == 0) {
            double bb = (double)bg2[0];
            topo[0 * NTOK + i] = (float)(red[0][0] + red[1][0] + bb);
            topo[2 * NTOK + i] = (float)(red[0][1] + red[1][1] + bb);
            topo[1 * NTOK + i] = (float)(red[2][0] + red[3][0] + bb);
            topo[3 * NTOK + i] = (float)(red[2][1] + red[3][1] + bb);
        }
    } else {
        int b2 = bid - 2048;
        int z = b2 >> 9, r2 = b2 & 511;
        const unsigned short* W = WT + z * 65536;
        const float* bias = z == 0 ? bq : z == 1 ? bk : bv;

        int lane = t & 63, w = t >> 6;
        int l15 = lane & 15, grp = lane >> 4;
        int mbase = (r2 & 127) * 64 + w * 16;
        int nbase = (r2 >> 7) * 64;
        f32x4 acc0 = {0,0,0,0}, acc1 = {0,0,0,0}, acc2 = {0,0,0,0}, acc3 = {0,0,0,0};
        const unsigned short* ap = xbf + (size_t)(mbase + l15) * DM + grp * 8;
        const unsigned short* bp2 = W + (size_t)(nbase + l15) * DM + grp * 8;
        #pragma unroll
        for (int k0 = 0; k0 < DM; k0 += 32) {
            bf16x8 af = *(const bf16x8*)(ap + k0);
            acc0 = MFMA16(af, *(const bf16x8*)(bp2 + k0), acc0, 0, 0, 0);
            acc1 = MFMA16(af, *(const bf16x8*)(bp2 + 16 * DM + k0), acc1, 0, 0, 0);
            acc2 = MFMA16(af, *(const bf16x8*)(bp2 + 32 * DM + k0), acc2, 0, 0, 0);
            acc3 = MFMA16(af, *(const bf16x8*)(bp2 + 48 * DM + k0), acc3, 0, 0, 0);
        }
        f32x4 accs[4] = {acc0, acc1, acc2, acc3};
        #pragma unroll
        for (int ct = 0; ct < 4; ++ct) {
            #pragma unroll
            for (int r = 0; r < 4; ++r) {
                int m = mbase + grp * 4 + r;
                int n = nbase + ct * 16 + l15;
                float v = accs[ct][r] + bias[n];
                if (z == 0) {
                    qo[(size_t)m * DM + n] = f2bf(v);
                } else {
                    int b = m >> 11, tok = m & 2047, h = n >> 6, d = n & 63;
                    int bh = (b << 2) + h;
                    if (z == 1) {
                        kt[(size_t)bh * 131072 + (tok >> 4) * 1024 + (tok & 15) * 64 + d] = f2bf(v);
                    } else {
                        vt3[(size_t)bh * 131072 + (tok >> 5) * 2048 + d * 32 + (tok & 31)] = f2bf(v);
                    }
                }
            }
        }
    }
}

// ---------------- top-k column mask (stable tie-break = lax.top_k), float4 scan ----------------
__global__ __launch_bounds__(256) void k_topk(const float* __restrict__ topo,
                                              uint32_t* __restrict__ colbits) {
    int b = blockIdx.y, t = threadIdx.x;
    int i = blockIdx.x * 256 + t;
    __shared__ float4 sc4[NTOK / 4];
    const float4* tp = (const float4*)(topo + b * NTOK);
    for (int j = t; j < NTOK / 4; j += 256) sc4[j] = tp[j];
    __syncthreads();
    float si = ((const float*)sc4)[i];
    int rank = 0;
    #pragma unroll 2
    for (int jj = 0; jj < NTOK / 4; ++jj) {
        float4 v = sc4[jj];
        int j0 = jj * 4;
        rank += (v.x > si) || (v.x == si && (j0    ) < i);
        rank += (v.y > si) || (v.y == si && (j0 + 1) < i);
        rank += (v.z > si) || (v.z == si && (j0 + 2) < i);
        rank += (v.w > si) || (v.w == si && (j0 + 3) < i);
    }
    unsigned long long m = __ballot(rank < 1024);
    int lane = t & 63;
    if (lane == 0)       colbits[b * 64 + (i >> 5)] = (uint32_t)m;
    else if (lane == 32) colbits[b * 64 + (i >> 5)] = (uint32_t)(m >> 32);
}

// ---------------- mask4 row writer (one block = one [b,h,i] row, 8 KB) ----------------
__device__ __forceinline__ void mask_row(int rowidx, const uint32_t* __restrict__ eb,
                                         const uint32_t* __restrict__ cb,
                                         float* __restrict__ mout) {
    int t = threadIdx.x;
    int b = rowidx >> 13;
    int i = rowidx & 2047;
    int j0 = t << 3;
    uint32_t mw = eb[i * 64 + (j0 >> 5)] | cb[b * 64 + (j0 >> 5)];
    int sh = j0 & 31;
    float4 v0, v1;
    v0.x = ((mw >> sh) & 1u) ? 1.f : 0.f;
    v0.y = ((mw >> (sh + 1)) & 1u) ? 1.f : 0.f;
    v0.z = ((mw >> (sh + 2)) & 1u) ? 1.f : 0.f;
    v0.w = ((mw >> (sh + 3)) & 1u) ? 1.f : 0.f;
    v1.x = ((mw >> (sh + 4)) & 1u) ? 1.f : 0.f;
    v1.y = ((mw >> (sh + 5)) & 1u) ? 1.f : 0.f;
    v1.z = ((mw >> (sh + 6)) & 1u) ? 1.f : 0.f;
    v1.w = ((mw >> (sh + 7)) & 1u) ? 1.f : 0.f;
    float* p = mout + (size_t)rowidx * NTOK + j0;
    *(float4*)p = v0;
    *(float4*)(p + 4) = v1;
}

// ---------------- fused: attention (LDS-staged K/V) + mask rows >= ROWS_B ----------------
__global__ __launch_bounds__(256) void k_attn_mask(const unsigned short* __restrict__ Q,
                                                   const unsigned short* __restrict__ KT,
                                                   const unsigned short* __restrict__ VT3,
                                                   const uint32_t* __restrict__ ebits,
                                                   const uint32_t* __restrict__ colbits,
                                                   float* __restrict__ po,
                                                   float* __restrict__ pl,
                                                   float* __restrict__ mout) {
    int bid = blockIdx.x;
    if (bid >= 2048) {
        mask_row(bid - 2048 + ROWS_B, ebits, colbits, mout);
        return;
    }
    __shared__ unsigned short ksh[2][2048];
    __shared__ unsigned short vsh[2][2048];
    int t = threadIdx.x;
    int lane = t & 63, w = t >> 6;
    int l15 = lane & 15, grp = lane >> 4;
    int ks = bid >> 9;
    int bh = (bid >> 5) & 15, b = bh >> 2, h = bh & 3;
    int q = (bid & 31) * 64 + w * 16 + l15;

    const unsigned short* qp = Q + (size_t)(b * NTOK + q) * DM + h * HD + grp * 8;
    bf16x8 qf0 = *(const bf16x8*)(qp);
    bf16x8 qf1 = *(const bf16x8*)(qp + 32);
    const unsigned short* Kt = KT + (size_t)bh * 131072;
    const unsigned short* Vt = VT3 + (size_t)bh * 131072;
    const uint32_t* eb = ebits + q * 64;
    const uint32_t* cbp = colbits + b * 64;

    int kb0 = ks * (NTOK / NKSL);
    int kso = (t * 16) ^ (((t >> 3) & 7) << 4);
    int vso = (t * 16) ^ (((t >> 2) & 7) << 4);
    int swz = (l15 & 7) << 4;

    {
        uint4 kv = *(const uint4*)(Kt + (size_t)(kb0 >> 4) * 1024 + t * 8);
        *(uint4*)((char*)&ksh[0][0] + kso) = kv;
        uint4 vv = *(const uint4*)(Vt + (size_t)(kb0 >> 5) * 2048 + t * 8);
        *(uint4*)((char*)&vsh[0][0] + vso) = vv;
    }
    __syncthreads();

    f32x4 o0 = {0,0,0,0}, o1 = {0,0,0,0}, o2 = {0,0,0,0}, o3 = {0,0,0,0};
    float psum = 0.f;

    for (int it = 0; it < NTOK / NKSL / 32; ++it) {
        int buf = it & 1;
        if (it + 1 < NTOK / NKSL / 32) {
            int kb = kb0 + (it + 1) * 32;
            uint4 kv = *(const uint4*)(Kt + (size_t)(kb >> 4) * 1024 + t * 8);
            *(uint4*)((char*)&ksh[buf ^ 1][0] + kso) = kv;
            uint4 vv = *(const uint4*)(Vt + (size_t)(kb >> 5) * 2048 + t * 8);
            *(uint4*)((char*)&vsh[buf ^ 1][0] + vso) = vv;
        }
        int kb = kb0 + it * 32;
        const char* kp = (const char*)&ksh[buf][0];
        const char* vp = (const char*)&vsh[buf][0];

        f32x4 st0 = {0,0,0,0}, st1 = {0,0,0,0};
        st0 = MFMA16(*(const bf16x8*)(kp + ((l15 * 128 + grp * 16) ^ swz)),        qf0, st0, 0, 0, 0);
        st0 = MFMA16(*(const bf16x8*)(kp + ((l15 * 128 + 64 + grp * 16) ^ swz)),   qf1, st0, 0, 0, 0);
        st1 = MFMA16(*(const bf16x8*)(kp + (((16 + l15) * 128 + grp * 16) ^ swz)), qf0, st1, 0, 0, 0);
        st1 = MFMA16(*(const bf16x8*)(kp + (((16 + l15) * 128 + 64 + grp * 16) ^ swz)), qf1, st1, 0, 0, 0);

        uint32_t mw = eb[kb >> 5] | cbp[kb >> 5];
        float p[8];
        #pragma unroll
        for (int r = 0; r < 4; ++r) {
            int p0 = grp * 4 + r;
            p[r]     = ((mw >> p0) & 1u)        ? __expf(st0[r] * 0.125f - 8.0f) : 0.f;
            p[4 + r] = ((mw >> (16 + p0)) & 1u) ? __expf(st1[r] * 0.125f - 8.0f) : 0.f;
        }
        #pragma unroll
        for (int j = 0; j < 8; ++j) psum += p[j];

        uint32_t pk00, pk01, pk10, pk11;
        asm("v_cvt_pk_bf16_f32 %0, %1, %2" : "=v"(pk00) : "v"(p[0]), "v"(p[1]));
        asm("v_cvt_pk_bf16_f32 %0, %1, %2" : "=v"(pk01) : "v"(p[2]), "v"(p[3]));
        asm("v_cvt_pk_bf16_f32 %0, %1, %2" : "=v"(pk10) : "v"(p[4]), "v"(p[5]));
        asm("v_cvt_pk_bf16_f32 %0, %1, %2" : "=v"(pk11) : "v"(p[6]), "v"(p[7]));
        union { uint32_t u[4]; bf16x8 v; } pf;
        #pragma unroll
        for (int wi = 0; wi < 4; ++wi) {
            int src = (((grp * 2 + (wi >> 1)) & 3) << 4) | l15;
            uint32_t lo = (uint32_t)__shfl((int)((wi & 1) ? pk01 : pk00), src);
            uint32_t hi = (uint32_t)__shfl((int)((wi & 1) ? pk11 : pk10), src);
            pf.u[wi] = (lane >= 32) ? hi : lo;
        }

        o0 = MFMA16(*(const bf16x8*)(vp + ((l15 * 64 + grp * 16) ^ swz)),          pf.v, o0, 0, 0, 0);
        o1 = MFMA16(*(const bf16x8*)(vp + (((16 + l15) * 64 + grp * 16) ^ swz)),   pf.v, o1, 0, 0, 0);
        o2 = MFMA16(*(const bf16x8*)(vp + (((32 + l15) * 64 + grp * 16) ^ swz)),   pf.v, o2, 0, 0, 0);
        o3 = MFMA16(*(const bf16x8*)(vp + (((48 + l15) * 64 + grp * 16) ^ swz)),   pf.v, o3, 0, 0, 0);
        __syncthreads();
    }
    psum += __shfl_xor(psum, 16);
    psum += __shfl_xor(psum, 32);

    float* pb = po + (((size_t)(ks * 16 + bh) * NTOK + q) * HD);
    *(f32x4*)(pb + 0 * 16 + grp * 4) = o0;
    *(f32x4*)(pb + 1 * 16 + grp * 4) = o1;
    *(f32x4*)(pb + 2 * 16 + grp * 4) = o2;
    *(f32x4*)(pb + 3 * 16 + grp * 4) = o3;
    if (grp == 0) pl[(size_t)(ks * 16 + bh) * NTOK + q] = psum;
}

// ---------------- combine K-slice partials -> normalized bf16 attention out ----------------
__global__ __launch_bounds__(256) void k_fin(const float* __restrict__ po,
                                             const float* __restrict__ pl,
                                             unsigned short* __restrict__ aoutb) {
    const size_t SL = (size_t)16 * NTOK * HD;
    const size_t SLP = (size_t)16 * NTOK;
    int tid = blockIdx.x * 256 + threadIdx.x;
    int dc = tid & 7;
    int q = (tid >> 3) & 2047;
    int bh = tid >> 14;
    size_t rb = ((size_t)bh * NTOK + q) * HD + dc * 8;
    float4 s0 = *(const float4*)(po + rb);
    float4 s1 = *(const float4*)(po + rb + 4);
    #pragma unroll
    for (int ks = 1; ks < NKSL; ++ks) {
        float4 a = *(const float4*)(po + ks * SL + rb);
        float4 c = *(const float4*)(po + ks * SL + rb + 4);
        s0.x += a.x; s0.y += a.y; s0.z += a.z; s0.w += a.w;
        s1.x += c.x; s1.y += c.y; s1.z += c.z; s1.w += c.w;
    }
    float l = 0.f;
    #pragma unroll
    for (int ks = 0; ks < NKSL; ++ks) l += pl[ks * SLP + (size_t)bh * NTOK + q];
    float inv = 1.f / l;
    int b = bh >> 2, h = bh & 3;
    union { ushort4 u4[2]; uint4 v; } out;
    out.u4[0].x = f2bf(s0.x * inv); out.u4[0].y = f2bf(s0.y * inv);
    out.u4[0].z = f2bf(s0.z * inv); out.u4[0].w = f2bf(s0.w * inv);
    out.u4[1].x = f2bf(s1.x * inv); out.u4[1].y = f2bf(s1.y * inv);
    out.u4[1].z = f2bf(s1.z * inv); out.u4[1].w = f2bf(s1.w * inv);
    *(uint4*)(aoutb + ((size_t)(b * NTOK + q) * DM) + h * HD + dc * 8) = out.v;
}

// ---------------- output projection GEMM body ----------------
__device__ __forceinline__ void gemm_o_body(int bid, const unsigned short* __restrict__ A,
                                            const unsigned short* __restrict__ WT,
                                            const float* __restrict__ bias,
                                            float* __restrict__ out) {
    int lane = threadIdx.x & 63, w = threadIdx.x >> 6;
    int l15 = lane & 15, grp = lane >> 4;
    int mbase = (bid & 127) * 64 + w * 16;
    int nbase = (bid >> 7) * 64;
    f32x4 acc0 = {0,0,0,0}, acc1 = {0,0,0,0}, acc2 = {0,0,0,0}, acc3 = {0,0,0,0};
    const unsigned short* ap = A + (size_t)(mbase + l15) * DM + grp * 8;
    const unsigned short* bp = WT + (size_t)(nbase + l15) * DM + grp * 8;
    #pragma unroll
    for (int k0 = 0; k0 < DM; k0 += 32) {
        bf16x8 af = *(const bf16x8*)(ap + k0);
        acc0 = MFMA16(af, *(const bf16x8*)(bp + k0), acc0, 0, 0, 0);
        acc1 = MFMA16(af, *(const bf16x8*)(bp + 16 * DM + k0), acc1, 0, 0, 0);
        acc2 = MFMA16(af, *(const bf16x8*)(bp + 32 * DM + k0), acc2, 0, 0, 0);
        acc3 = MFMA16(af, *(const bf16x8*)(bp + 48 * DM + k0), acc3, 0, 0, 0);
    }
    f32x4 accs[4] = {acc0, acc1, acc2, acc3};
    #pragma unroll
    for (int ct = 0; ct < 4; ++ct) {
        #pragma unroll
        for (int r = 0; r < 4; ++r) {
            int m = mbase + grp * 4 + r;
            int n = nbase + ct * 16 + l15;
            out[(size_t)m * DM + n] = accs[ct][r] + bias[n];
        }
    }
}

// ---------------- fused: output GEMM (blocks [0,512)) + mask rows [ROWS_A, ROWS_B) ----------------
__global__ __launch_bounds__(256) void k_gemm_mask(const unsigned short* __restrict__ A,
                                                   const unsigned short* __restrict__ WT,
                                                   const float* __restrict__ bias,
                                                   float* __restrict__ out,
                                                   const uint32_t* __restrict__ ebits,
                                                   const uint32_t* __restrict__ colbits,
                                                   float* __restrict__ mout) {
    int bid = blockIdx.x;
    if (bid < 512) {
        gemm_o_body(bid, A, WT, bias, out);
    } else {
        mask_row(bid - 512 + ROWS_A, ebits, colbits, mout);
    }
}

// ---------------- deferred mask4 rows [0, ROWS_A): overwrite qbf..aoutb last ----------------
__global__ void k_mask4b(const uint32_t* __restrict__ ebits, const uint32_t* __restrict__ colbits,
                         float* __restrict__ mout) {
    mask_row(blockIdx.x, ebits, colbits, mout);
}

extern "C" void kernel_launch(void* const* d_in, const int* in_sizes, int n_in,
                              void* d_out, int out_size, void* d_ws, size_t ws_size,
                              hipStream_t stream) {
    const float* x   = (const float*)d_in[0];
    const int*   ei  = (const int*)d_in[1];          // int64 in reference -> int32 here
    const float* Wq  = (const float*)d_in[2];
    const float* bq  = (const float*)d_in[3];
    const float* Wk  = (const float*)d_in[4];
    const float* bk  = (const float*)d_in[5];
    const float* Wv  = (const float*)d_in[6];
    const float* bv  = (const float*)d_in[7];
    const float* Wo  = (const float*)d_in[8];
    const float* bo  = (const float*)d_in[9];
    const float* Wg1 = (const float*)d_in[10];
    const float* bg1 = (const float*)d_in[11];
    const float* Wg2 = (const float*)d_in[12];
    const float* bg2 = (const float*)d_in[13];

    float* out0  = (float*)d_out;
    float* mask4 = out0 + (size_t)NB * NTOK * DM;

    // Scratch layout in the mask4 region (row = 8 KB):
    //  rows [0, ROWS_A)      : qbf kt vt3 wt aoutb  (live until gemm) -> k_mask4b last
    //  rows [ROWS_A, ROWS_B) : po pl                (dead after fin)  -> fused w/ gemm
    //  rows [ROWS_B, 32768)  : xbf scol y (dead after gnn_qkv) + free -> fused w/ attn
    uint8_t* big = (uint8_t*)mask4;
    unsigned short* qbf   = (unsigned short*)(big);                              // 0..4 MB
    unsigned short* kt    = (unsigned short*)(big + (4u  << 20));                // 4..8 MB
    unsigned short* vt3   = (unsigned short*)(big + (8u  << 20));                // 8..12 MB
    unsigned short* wt    = (unsigned short*)(big + (12u << 20));                // 12..12.5 MB
    unsigned short* aoutb = (unsigned short*)(big + (12u << 20) + (512u << 10)); // 12.5..16.5 MB
    float*          po    = (float*)         (big + (16u << 20) + (512u << 10)); // 16.5..48.5 MB
    float*          pl    = (float*)         (big + (48u << 20) + (512u << 10)); // 48.5..48.75 MB
    unsigned short* xbf   = (unsigned short*)(big + (49u << 20));                // 49..53 MB
    uint32_t*       scol  = (uint32_t*)      (big + (53u << 20));                // 53..54 MB
    float*          y     = (float*)         (big + (54u << 20));                // 54..58 MB

    // Small scratch in d_ws
    uint8_t* ws = (uint8_t*)d_ws;
    uint32_t* cursor  = (uint32_t*)(ws);               // 8 KB  (atomic; zeroed by k_prep)
    uint32_t* ebits   = (uint32_t*)(ws + (16u << 10)); // 512 KB (atomic; zeroed by k_prep)
    uint32_t* colbits = (uint32_t*)(ws + (528u << 10));// 256 B (fully written)
    float*    topo    = (float*)(ws + (532u << 10));   // 32 KB (fully written)

    k_prep<<<1668, 256, 0, stream>>>(x, xbf, Wq, Wk, Wv, Wo, wt, (float4*)ws, Wg1, y);
    k_edges<<<256, 256, 0, stream>>>(ei, cursor, scol, ebits);
    k_gnn_qkv<<<3584, 256, 0, stream>>>(y, cursor, scol, bg1, Wg2, bg2, topo,
                                        xbf, wt, bq, bk, bv, qbf, kt, vt3);
    k_topk<<<dim3(8, 4), 256, 0, stream>>>(topo, colbits);
    k_attn_mask<<<2048 + (32768 - ROWS_B), 256, 0, stream>>>(qbf, kt, vt3, ebits, colbits,
                                                             po, pl, mask4);
    k_fin<<<1024, 256, 0, stream>>>(po, pl, aoutb);
    k_gemm_mask<<<512 + (ROWS_B - ROWS_A), 256, 0, stream>>>(aoutb, wt + 196608, bo, out0,
                                                             ebits, colbits, mask4);
    k_mask4b<<<ROWS_A, 256, 0, stream>>>(ebits, colbits, mask4);
}